// Round 11
// baseline (1090.620 us; speedup 1.0000x reference)
//
#include <hip/hip_runtime.h>
#include <hip/hip_bf16.h>

constexpr int N_NODES    = 500000;
constexpr int N_EDGES    = 8000000;
constexpr int NUM_GRAPHS = 512;

constexpr int BSHIFT = 9;                               // 512 nodes / bucket
constexpr int BSIZE  = 1 << BSHIFT;                     // 512
constexpr int NBKT   = (N_NODES + BSIZE - 1) / BSIZE;   // 977
constexpr int EPB    = 4096;                            // edges per block (pass A)
constexpr int NBLK_A = (N_EDGES + EPB - 1) / EPB;       // 1954
constexpr int NH     = NBKT * NBLK_A;                   // 1,909,058
constexpr int SCAN_B = 256;
constexpr int NSB    = (NH + SCAN_B - 1) / SCAN_B;      // 7458

// ---- bf16 helpers (bit-level, RNE pack) ----
__device__ __forceinline__ float bf_lo(unsigned u) { return __uint_as_float(u << 16); }
__device__ __forceinline__ float bf_hi(unsigned u) { return __uint_as_float(u & 0xFFFF0000u); }
__device__ __forceinline__ unsigned short f2bf(float f) {
  unsigned u = __float_as_uint(f);
  return (unsigned short)((u + 0x7FFFu + ((u >> 16) & 1u)) >> 16);
}
__device__ __forceinline__ unsigned packbf(float a, float b) {
  return (unsigned)f2bf(a) | ((unsigned)f2bf(b) << 16);
}

// ---- pass A1: per-block coarse histogram (LDS atomics only) ----
__global__ void k_hist(const int* __restrict__ dst, int* __restrict__ H) {
  __shared__ int h[NBKT];
  for (int i = threadIdx.x; i < NBKT; i += blockDim.x) h[i] = 0;
  __syncthreads();
  int e0 = blockIdx.x * EPB;
  int e1 = min(e0 + EPB, N_EDGES);
  for (int e = e0 + threadIdx.x; e < e1; e += blockDim.x)
    atomicAdd(&h[dst[e] >> BSHIFT], 1);
  __syncthreads();
  for (int i = threadIdx.x; i < NBKT; i += blockDim.x)
    H[i * NBLK_A + blockIdx.x] = h[i];                  // bucket-major
}

// ---- exclusive scan of H (NH ints): 3 kernels ----
__global__ void k_scan1(const int* __restrict__ in, int* __restrict__ out,
                        int* __restrict__ bsum, int n) {
  __shared__ int tmp[SCAN_B];
  int t = threadIdx.x;
  int i = blockIdx.x * SCAN_B + t;
  int v = (i < n) ? in[i] : 0;
  tmp[t] = v;
  __syncthreads();
  for (int off = 1; off < SCAN_B; off <<= 1) {
    int a = (t >= off) ? tmp[t - off] : 0;
    __syncthreads();
    tmp[t] += a;
    __syncthreads();
  }
  if (i < n) out[i] = tmp[t] - v;
  if (t == SCAN_B - 1) bsum[blockIdx.x] = tmp[t];
}

__global__ void __launch_bounds__(1024) k_scan2(int* __restrict__ bsum, int nb) {
  __shared__ int tmp[1024];
  int t = threadIdx.x;
  int carry = 0;
  for (int base = 0; base < nb; base += 1024) {
    int i = base + t;
    int v = (i < nb) ? bsum[i] : 0;
    tmp[t] = v;
    __syncthreads();
    for (int off = 1; off < 1024; off <<= 1) {
      int a = (t >= off) ? tmp[t - off] : 0;
      __syncthreads();
      tmp[t] += a;
      __syncthreads();
    }
    if (i < nb) bsum[i] = carry + tmp[t] - v;
    carry += tmp[1023];
    __syncthreads();
  }
}

__global__ void k_scan3(int* __restrict__ out, const int* __restrict__ bsum, int n) {
  int i = blockIdx.x * blockDim.x + threadIdx.x;
  if (i < n) out[i] += bsum[i >> 8];
}

// ---- pass A3: scatter edges into buckets (LDS cursors), packed pairs ----
__global__ void k_scatter_bkt(const int* __restrict__ src, const int* __restrict__ dst,
                              const int* __restrict__ S, int* __restrict__ pairs) {
  __shared__ int cur[NBKT];
  for (int i = threadIdx.x; i < NBKT; i += blockDim.x)
    cur[i] = S[i * NBLK_A + blockIdx.x];
  __syncthreads();
  int e0 = blockIdx.x * EPB;
  int e1 = min(e0 + EPB, N_EDGES);
  for (int e = e0 + threadIdx.x; e < e1; e += blockDim.x) {
    int d = dst[e];
    int pos = atomicAdd(&cur[d >> BSHIFT], 1);
    pairs[pos] = ((d & (BSIZE - 1)) << 19) | src[e];    // src < 2^19, dlow 9 bits
  }
}

// ---- bucket boundaries (Sarr dies after this) ----
__global__ void k_bstart(const int* __restrict__ S, int* __restrict__ bstart) {
  int k = blockIdx.x * blockDim.x + threadIdx.x;
  if (k < NBKT) bstart[k] = S[k * NBLK_A];
  if (k == NBKT) bstart[k] = N_EDGES;
}

// ---- per-bucket in-degree (replaces csr pass 1) ----
__global__ void k_degb(const int* __restrict__ pairs, const int* __restrict__ bstart,
                       int* __restrict__ cnt) {
  __shared__ int h[BSIZE];
  int t = threadIdx.x, bkt = blockIdx.x;
  h[t] = 0; h[t + 256] = 0;
  __syncthreads();
  int e0 = bstart[bkt], e1 = bstart[bkt + 1];
  for (int e = e0 + t; e < e1; e += 256) atomicAdd(&h[pairs[e] >> 19], 1);
  __syncthreads();
  int n0 = bkt << BSHIFT;
  for (int i = t; i < BSIZE; i += 256) {
    int n = n0 + i;
    if (n < N_NODES) cnt[n] = h[i];
  }
}

// ---- dinv + pre-scaled bf16 features: xsb[n] = {bf(di*x0), bf(di*x1), bf(di*x2), 0} ----
__global__ void k_prep(const int* __restrict__ cnt, const float* __restrict__ x,
                       float* __restrict__ dinv, unsigned* __restrict__ xsb) {
  int n = blockIdx.x * blockDim.x + threadIdx.x;
  if (n >= N_NODES) return;
  float di = rsqrtf((float)cnt[n] + 1.0f);
  dinv[n] = di;
  const float* xs = x + (size_t)n * 3;
  uint2 v = make_uint2(packbf(di * xs[0], di * xs[1]), packbf(di * xs[2], 0.0f));
  *(uint2*)(xsb + (size_t)n * 2) = v;
}

// ---- graph segment boundaries ----
__global__ void k_bounds(const int* __restrict__ batch, int* __restrict__ start) {
  int g = blockIdx.x * blockDim.x + threadIdx.x;
  if (g > NUM_GRAPHS) return;
  int lo = 0, hi = N_NODES;
  while (lo < hi) { int mid = (lo + hi) >> 1; if (batch[mid] < g) lo = mid + 1; else hi = mid; }
  start[g] = lo;
}

// ---- layer 1 aggregate: per-bucket LDS accumulation (replaces gather1 + csr sort) ----
__global__ void __launch_bounds__(512)
k_agg1(const int* __restrict__ pairs, const int* __restrict__ bstart,
       const unsigned* __restrict__ xsb, float* __restrict__ A1) {
  __shared__ float acc[3][BSIZE];
  int t = threadIdx.x, bkt = blockIdx.x;
  acc[0][t] = 0.f; acc[1][t] = 0.f; acc[2][t] = 0.f;
  __syncthreads();
  int e0 = bstart[bkt], e1 = bstart[bkt + 1];
  for (int e = e0 + t; e < e1; e += 512) {
    int p = pairs[e];
    int s = p & 0x7FFFF, d = p >> 19;
    uint2 q = *(const uint2*)&xsb[(size_t)s * 2];
    atomicAdd(&acc[0][d], bf_lo(q.x));
    atomicAdd(&acc[1][d], bf_hi(q.x));
    atomicAdd(&acc[2][d], bf_lo(q.y));
  }
  __syncthreads();
  int n = (bkt << BSHIFT) + t;
  if (n < N_NODES)
    *(float4*)&A1[(size_t)n * 4] = make_float4(acc[0][t], acc[1][t], acc[2][t], 0.f);
}

// ---- layer 1 finalize: u(bf16) = di * relu( (di*(A1+xs)) @ W1 + b1 ) ----
__global__ void k_fin1(const float* __restrict__ A1, const unsigned* __restrict__ xsb,
                       const float* __restrict__ dinv, const float* __restrict__ W1,
                       const float* __restrict__ b1, unsigned* __restrict__ ub) {
  unsigned t = blockIdx.x * blockDim.x + threadIdx.x;
  unsigned n = t >> 3;
  int h = t & 7;
  if (n >= (unsigned)N_NODES) return;
  float di = dinv[n];
  float4 a = *(const float4*)&A1[(size_t)n * 4];
  uint2 xq = *(const uint2*)&xsb[(size_t)n * 2];
  float t0 = di * (a.x + bf_lo(xq.x));
  float t1 = di * (a.y + bf_hi(xq.x));
  float t2 = di * (a.z + bf_lo(xq.y));
  int f = 2 * h;
  float v0 = t0 * W1[f]     + t1 * W1[16 + f]     + t2 * W1[32 + f]     + b1[f];
  float v1 = t0 * W1[f + 1] + t1 * W1[16 + f + 1] + t2 * W1[32 + f + 1] + b1[f + 1];
  ub[(size_t)n * 8 + h] = packbf(di * fmaxf(v0, 0.0f), di * fmaxf(v1, 0.0f));
}

// ---- layer 2 aggregate: per-bucket LDS accumulation (replaces gather2 + csr sort) ----
// acc[k][dlow]: bank = dlow%32 -> ~2-way conflicts across random lanes (free, m136).
__global__ void __launch_bounds__(512)
k_agg2(const int* __restrict__ pairs, const int* __restrict__ bstart,
       const unsigned* __restrict__ ub, float* __restrict__ A2) {
  __shared__ float acc[16][BSIZE];                      // 32 KB
  int t = threadIdx.x, bkt = blockIdx.x;
#pragma unroll
  for (int k = 0; k < 16; ++k) acc[k][t] = 0.f;
  __syncthreads();
  int e0 = bstart[bkt], e1 = bstart[bkt + 1];
  for (int e = e0 + t; e < e1; e += 512) {
    int p = pairs[e];
    int s = p & 0x7FFFF, d = p >> 19;
    const uint4* up = (const uint4*)&ub[(size_t)s * 8];
    uint4 w0 = up[0], w1 = up[1];
    atomicAdd(&acc[0][d],  bf_lo(w0.x)); atomicAdd(&acc[1][d],  bf_hi(w0.x));
    atomicAdd(&acc[2][d],  bf_lo(w0.y)); atomicAdd(&acc[3][d],  bf_hi(w0.y));
    atomicAdd(&acc[4][d],  bf_lo(w0.z)); atomicAdd(&acc[5][d],  bf_hi(w0.z));
    atomicAdd(&acc[6][d],  bf_lo(w0.w)); atomicAdd(&acc[7][d],  bf_hi(w0.w));
    atomicAdd(&acc[8][d],  bf_lo(w1.x)); atomicAdd(&acc[9][d],  bf_hi(w1.x));
    atomicAdd(&acc[10][d], bf_lo(w1.y)); atomicAdd(&acc[11][d], bf_hi(w1.y));
    atomicAdd(&acc[12][d], bf_lo(w1.z)); atomicAdd(&acc[13][d], bf_hi(w1.z));
    atomicAdd(&acc[14][d], bf_lo(w1.w)); atomicAdd(&acc[15][d], bf_hi(w1.w));
  }
  __syncthreads();
  int n = (bkt << BSHIFT) + t;
  if (n < N_NODES) {
    float* o = A2 + (size_t)n * 16;
    *(float4*)(o)      = make_float4(acc[0][t],  acc[1][t],  acc[2][t],  acc[3][t]);
    *(float4*)(o + 4)  = make_float4(acc[4][t],  acc[5][t],  acc[6][t],  acc[7][t]);
    *(float4*)(o + 8)  = make_float4(acc[8][t],  acc[9][t],  acc[10][t], acc[11][t]);
    *(float4*)(o + 12) = make_float4(acc[12][t], acc[13][t], acc[14][t], acc[15][t]);
  }
}

// ---- pool v2: 128 contiguous nodes/block, 8 subgroups x 32 features ----
__global__ void k_pool2(const unsigned* __restrict__ ub, const float* __restrict__ A2,
                        const float* __restrict__ W2, const float* __restrict__ b2,
                        const float* __restrict__ dinv, const int* __restrict__ batch,
                        float* __restrict__ sums) {
  int f = threadIdx.x & 31, sub = threadIdx.x >> 5;
  int n0 = blockIdx.x * 128 + sub * 16;
  int n1 = min(n0 + 16, N_NODES);
  if (n0 >= n1) return;
  float w2col[16];
#pragma unroll
  for (int k = 0; k < 16; ++k) w2col[k] = W2[k * 32 + f];
  float bf = b2[f];
  int cur = batch[n0];
  float acc = 0.0f;
  for (int n = n0; n < n1; ++n) {
    int g = batch[n];
    if (g != cur) { atomicAdd(&sums[(size_t)cur * 32 + f], acc); acc = 0.0f; cur = g; }
    float di = dinv[n];
    const float4* a2p = (const float4*)(A2 + (size_t)n * 16);
    float4 aa0 = a2p[0], aa1 = a2p[1], aa2 = a2p[2], aa3 = a2p[3];
    const uint4* urp = (const uint4*)(ub + (size_t)n * 8);
    uint4 uq = urp[0], uq2 = urp[1];
    float un[16];
    un[0] = bf_lo(uq.x);  un[1] = bf_hi(uq.x);
    un[2] = bf_lo(uq.y);  un[3] = bf_hi(uq.y);
    un[4] = bf_lo(uq.z);  un[5] = bf_hi(uq.z);
    un[6] = bf_lo(uq.w);  un[7] = bf_hi(uq.w);
    un[8]  = bf_lo(uq2.x); un[9]  = bf_hi(uq2.x);
    un[10] = bf_lo(uq2.y); un[11] = bf_hi(uq2.y);
    un[12] = bf_lo(uq2.z); un[13] = bf_hi(uq2.z);
    un[14] = bf_lo(uq2.w); un[15] = bf_hi(uq2.w);
    float am[16] = {aa0.x, aa0.y, aa0.z, aa0.w, aa1.x, aa1.y, aa1.z, aa1.w,
                    aa2.x, aa2.y, aa2.z, aa2.w, aa3.x, aa3.y, aa3.z, aa3.w};
    float v = bf;
#pragma unroll
    for (int k = 0; k < 16; ++k) v += di * (am[k] + un[k]) * w2col[k];
    acc += fmaxf(v, 0.0f);
  }
  atomicAdd(&sums[(size_t)cur * 32 + f], acc);
}

// ---- final MLP + log_softmax (counts from gstart) ----
__global__ void k_mlp(const float* __restrict__ sums, const int* __restrict__ gstart,
                      const float* __restrict__ fW1, const float* __restrict__ fb1,
                      const float* __restrict__ fW2, const float* __restrict__ fb2,
                      float* __restrict__ out) {
  __shared__ float w1s[32 * 64];
  __shared__ float w2s[64 * 3];
  __shared__ float b1s[64];
  __shared__ float b2s[3];
  for (int i = threadIdx.x; i < 32 * 64; i += blockDim.x) w1s[i] = fW1[i];
  for (int i = threadIdx.x; i < 64 * 3; i += blockDim.x) w2s[i] = fW2[i];
  for (int i = threadIdx.x; i < 64; i += blockDim.x) b1s[i] = fb1[i];
  for (int i = threadIdx.x; i < 3; i += blockDim.x) b2s[i] = fb2[i];
  __syncthreads();
  int g = blockIdx.x * blockDim.x + threadIdx.x;
  if (g >= NUM_GRAPHS) return;
  float c = fmaxf((float)(gstart[g + 1] - gstart[g]), 1.0f);
  float p[32];
#pragma unroll
  for (int i = 0; i < 32; ++i) p[i] = sums[(size_t)g * 32 + i] / c;
  float z2[3] = {b2s[0], b2s[1], b2s[2]};
  for (int j = 0; j < 64; ++j) {
    float a = b1s[j];
#pragma unroll
    for (int i = 0; i < 32; ++i) a += p[i] * w1s[i * 64 + j];
    a = fmaxf(a, 0.0f);
#pragma unroll
    for (int k = 0; k < 3; ++k) z2[k] += a * w2s[j * 3 + k];
  }
  float m = fmaxf(fmaxf(z2[0], z2[1]), z2[2]);
  float l = logf(expf(z2[0] - m) + expf(z2[1] - m) + expf(z2[2] - m));
#pragma unroll
  for (int k = 0; k < 3; ++k) out[(size_t)g * 3 + k] = z2[k] - m - l;
}

extern "C" void kernel_launch(void* const* d_in, const int* in_sizes, int n_in,
                              void* d_out, int out_size, void* d_ws, size_t ws_size,
                              hipStream_t stream) {
  const float* x     = (const float*)d_in[0];
  const int*   ei    = (const int*)d_in[1];   // [2, E]
  const int*   batch = (const int*)d_in[2];
  const float* W1    = (const float*)d_in[3];
  const float* b1    = (const float*)d_in[4];
  const float* W2    = (const float*)d_in[5];
  const float* b2    = (const float*)d_in[6];
  const float* fW1   = (const float*)d_in[7];
  const float* fb1   = (const float*)d_in[8];
  const float* fW2   = (const float*)d_in[9];
  const float* fb2   = (const float*)d_in[10];
  const int* src = ei;
  const int* dst = ei + N_EDGES;

  // ---- workspace layout (≈98 MB) ----
  float* ws       = (float*)d_ws;
  float* dinv     = ws;                           // 524,288 f
  unsigned* xsb   = (unsigned*)(dinv + 524288);   // 1,048,576 u32 (2/node)
  unsigned* ub    = xsb + 1048576;                // 4,194,304 u32 (8/node)
  float* A1       = (float*)(ub + 4194304);       // 2,097,152 f
  float* sums     = A1 + 2097152;                 // 16384
  int* cnt        = (int*)(sums + 16384);         // 524,288
  int* gstart     = cnt + 524288;                 // 1024 (513 used)
  int* bstart     = gstart + 1024;                // 1024 (978 used)
  int* pairs      = bstart + 1024;                // 8,000,000
  float* A2       = (float*)(pairs + 8000000);    // 8,000,000 f (32 MB)
  // scan scratch aliases A2 zone (dead before k_agg2 writes A2):
  int* H    = (int*)A2;                           // NH = 1,909,058
  int* Sarr = H + 1909760;                        // 1,909,058 used
  int* bsum = Sarr + 1909760;                     // 7,458 used (total 3,826,978 < 8M)

  hipMemsetAsync(sums, 0, (size_t)NUM_GRAPHS * 32 * 4, stream);

  const int B = 256;
  k_hist<<<NBLK_A, B, 0, stream>>>(dst, H);
  k_scan1<<<NSB, SCAN_B, 0, stream>>>(H, Sarr, bsum, NH);
  k_scan2<<<1, 1024, 0, stream>>>(bsum, NSB);
  k_scan3<<<(NH + B - 1) / B, B, 0, stream>>>(Sarr, bsum, NH);
  k_scatter_bkt<<<NBLK_A, B, 0, stream>>>(src, dst, Sarr, pairs);
  k_bstart<<<(NBKT + 1 + B - 1) / B, B, 0, stream>>>(Sarr, bstart);
  k_degb<<<NBKT, B, 0, stream>>>(pairs, bstart, cnt);
  k_prep<<<(N_NODES + B - 1) / B, B, 0, stream>>>(cnt, x, dinv, xsb);
  k_bounds<<<(NUM_GRAPHS + 1 + B - 1) / B, B, 0, stream>>>(batch, gstart);
  k_agg1<<<NBKT, 512, 0, stream>>>(pairs, bstart, xsb, A1);
  k_fin1<<<((size_t)N_NODES * 8 + B - 1) / B, B, 0, stream>>>(A1, xsb, dinv, W1, b1, ub);
  k_agg2<<<NBKT, 512, 0, stream>>>(pairs, bstart, ub, A2);
  k_pool2<<<(N_NODES + 127) / 128, B, 0, stream>>>(ub, A2, W2, b2, dinv, batch, sums);
  k_mlp<<<(NUM_GRAPHS + B - 1) / B, B, 0, stream>>>(sums, gstart, fW1, fb1, fW2, fb2, (float*)d_out);
}

// Round 12
// 484.893 us; speedup vs baseline: 2.2492x; 2.2492x over previous
//
#include <hip/hip_runtime.h>
#include <hip/hip_bf16.h>

constexpr int N_NODES    = 500000;
constexpr int N_EDGES    = 8000000;
constexpr int NUM_GRAPHS = 512;

constexpr int BSHIFT = 12;                              // 4096 nodes / coarse bucket
constexpr int BSIZE  = 1 << BSHIFT;
constexpr int NBKT   = (N_NODES + BSIZE - 1) / BSIZE;   // 123
constexpr int EPB    = 4096;                            // edges per block (pass A)
constexpr int NBLK_A = (N_EDGES + EPB - 1) / EPB;       // 1954
constexpr int NH     = NBKT * NBLK_A;                   // 240342
constexpr int SCAN_B = 256;
constexpr int NSB    = (NH + SCAN_B - 1) / SCAN_B;      // 939

// ---- bf16 helpers (bit-level, RNE pack) ----
__device__ __forceinline__ float bf_lo(unsigned u) { return __uint_as_float(u << 16); }
__device__ __forceinline__ float bf_hi(unsigned u) { return __uint_as_float(u & 0xFFFF0000u); }
__device__ __forceinline__ unsigned short f2bf(float f) {
  unsigned u = __float_as_uint(f);
  return (unsigned short)((u + 0x7FFFu + ((u >> 16) & 1u)) >> 16);
}
__device__ __forceinline__ unsigned packbf(float a, float b) {
  return (unsigned)f2bf(a) | ((unsigned)f2bf(b) << 16);
}

// ---- pass A1: per-block coarse histogram (LDS atomics only) ----
__global__ void k_hist(const int* __restrict__ dst, int* __restrict__ H) {
  __shared__ int h[NBKT];
  for (int i = threadIdx.x; i < NBKT; i += blockDim.x) h[i] = 0;
  __syncthreads();
  int e0 = blockIdx.x * EPB;
  int e1 = min(e0 + EPB, N_EDGES);
  for (int e = e0 + threadIdx.x; e < e1; e += blockDim.x)
    atomicAdd(&h[dst[e] >> BSHIFT], 1);
  __syncthreads();
  for (int i = threadIdx.x; i < NBKT; i += blockDim.x)
    H[i * NBLK_A + blockIdx.x] = h[i];                  // bucket-major
}

// ---- exclusive scan of H (NH ints): 3 kernels ----
__global__ void k_scan1(const int* __restrict__ in, int* __restrict__ out,
                        int* __restrict__ bsum, int n) {
  __shared__ int tmp[SCAN_B];
  int t = threadIdx.x;
  int i = blockIdx.x * SCAN_B + t;
  int v = (i < n) ? in[i] : 0;
  tmp[t] = v;
  __syncthreads();
  for (int off = 1; off < SCAN_B; off <<= 1) {
    int a = (t >= off) ? tmp[t - off] : 0;
    __syncthreads();
    tmp[t] += a;
    __syncthreads();
  }
  if (i < n) out[i] = tmp[t] - v;
  if (t == SCAN_B - 1) bsum[blockIdx.x] = tmp[t];
}

__global__ void k_scan2(int* __restrict__ bsum, int nb) {  // in-place exclusive
  __shared__ int tmp[SCAN_B];
  int t = threadIdx.x;
  int carry = 0;
  for (int base = 0; base < nb; base += SCAN_B) {
    int i = base + t;
    int v = (i < nb) ? bsum[i] : 0;
    tmp[t] = v;
    __syncthreads();
    for (int off = 1; off < SCAN_B; off <<= 1) {
      int a = (t >= off) ? tmp[t - off] : 0;
      __syncthreads();
      tmp[t] += a;
      __syncthreads();
    }
    if (i < nb) bsum[i] = carry + tmp[t] - v;
    carry += tmp[SCAN_B - 1];
    __syncthreads();
  }
}

__global__ void k_scan3(int* __restrict__ out, const int* __restrict__ bsum, int n) {
  int i = blockIdx.x * blockDim.x + threadIdx.x;
  if (i < n) out[i] += bsum[i >> 8];
}

// ---- pass A3 v2: block-local counting sort, then CONTIGUOUS per-bucket writes ----
__global__ void k_scatter_bkt(const int* __restrict__ src, const int* __restrict__ dst,
                              const int* __restrict__ S, int* __restrict__ pairs) {
  __shared__ int lcnt[128];            // per-bucket count, then reused as cursor
  __shared__ int lofs[128];            // exclusive local scan
  __shared__ int base[128];            // global base for (bucket, this block)
  __shared__ int pout[EPB];            // reordered pairs (16 KB)
  __shared__ unsigned char bout[EPB];  // bucket id per output slot (4 KB)
  int t = threadIdx.x;
  int blk = blockIdx.x;
  int e0 = blk * EPB;
  int e1 = min(e0 + EPB, N_EDGES);
  int ne = e1 - e0;
  if (t < 128) lcnt[t] = 0;
  __syncthreads();
  // phase A: local histogram
  for (int e = e0 + t; e < e1; e += 256)
    atomicAdd(&lcnt[dst[e] >> BSHIFT], 1);
  __syncthreads();
  // scan (inclusive over 128 via Hillis-Steele, then exclusive)
  if (t < 128) lofs[t] = lcnt[t];
  __syncthreads();
  for (int off = 1; off < 128; off <<= 1) {
    int v = (t < 128 && t >= off) ? lofs[t - off] : 0;
    __syncthreads();
    if (t < 128) lofs[t] += v;
    __syncthreads();
  }
  if (t < 128) {
    lofs[t] -= lcnt[t];                              // exclusive
    base[t] = (t < NBKT) ? S[t * NBLK_A + blk] : 0;  // global cursor base
    lcnt[t] = 0;                                     // reuse as local cursor
  }
  __syncthreads();
  // phase B: rank + reorder into LDS
  for (int e = e0 + t; e < e1; e += 256) {
    int d = dst[e], s = src[e];
    int b = d >> BSHIFT;
    int r = atomicAdd(&lcnt[b], 1);
    int q = lofs[b] + r;
    pout[q] = ((d & (BSIZE - 1)) << 19) | s;         // s < 2^19
    bout[q] = (unsigned char)b;
  }
  __syncthreads();
  // phase C: contiguous global writes per bucket run
  for (int li = t; li < ne; li += 256) {
    int b = bout[li];
    pairs[base[b] + (li - lofs[b])] = pout[li];
  }
}

// ---- pass B: per-bucket CSR finalize (one block per bucket, 1024 threads) ----
__global__ void __launch_bounds__(1024)
k_csr(const int* __restrict__ pairs, const int* __restrict__ S,
      int* __restrict__ ssrc, int* __restrict__ cnt, int* __restrict__ offs) {
  __shared__ int hist[BSIZE];
  __shared__ int tmp[1024];
  int t = threadIdx.x;
  int bkt = blockIdx.x;
  int n0 = bkt << BSHIFT;
  int e0 = S[bkt * NBLK_A];
  int e1 = (bkt + 1 < NBKT) ? S[(bkt + 1) * NBLK_A] : N_EDGES;
#pragma unroll
  for (int j = 0; j < 4; ++j) hist[t + j * 1024] = 0;
  __syncthreads();
  for (int e = e0 + t; e < e1; e += 1024)
    atomicAdd(&hist[pairs[e] >> 19], 1);
  __syncthreads();
  int c0 = hist[4 * t], c1 = hist[4 * t + 1], c2 = hist[4 * t + 2], c3 = hist[4 * t + 3];
  int tsum = c0 + c1 + c2 + c3;
  tmp[t] = tsum;
  __syncthreads();
  for (int off = 1; off < 1024; off <<= 1) {
    int a = (t >= off) ? tmp[t - off] : 0;
    __syncthreads();
    tmp[t] += a;
    __syncthreads();
  }
  int tbase = tmp[t] - tsum;     // exclusive over threads
  int o0 = tbase, o1 = tbase + c0, o2 = o1 + c1, o3 = o2 + c2;
  hist[4 * t] = o0; hist[4 * t + 1] = o1; hist[4 * t + 2] = o2; hist[4 * t + 3] = o3;
  int oo[4] = {o0, o1, o2, o3};
  int cc[4] = {c0, c1, c2, c3};
#pragma unroll
  for (int j = 0; j < 4; ++j) {
    int n = n0 + 4 * t + j;
    if (n < N_NODES) { cnt[n] = cc[j]; offs[n] = e0 + oo[j]; }
  }
  __syncthreads();
  for (int e = e0 + t; e < e1; e += 1024) {
    int p = pairs[e];
    int r = atomicAdd(&hist[p >> 19], 1);
    ssrc[e0 + r] = p & 0x7FFFF;
  }
  if (bkt == 0 && t == 0) offs[N_NODES] = N_EDGES;
}

// ---- dinv + pre-scaled bf16 features: xsb[n] = {bf(di*x0), bf(di*x1), bf(di*x2), 0} ----
__global__ void k_prep(const int* __restrict__ cnt, const float* __restrict__ x,
                       float* __restrict__ dinv, unsigned* __restrict__ xsb) {
  int n = blockIdx.x * blockDim.x + threadIdx.x;
  if (n >= N_NODES) return;
  float di = rsqrtf((float)cnt[n] + 1.0f);
  dinv[n] = di;
  const float* xs = x + (size_t)n * 3;
  uint2 v = make_uint2(packbf(di * xs[0], di * xs[1]), packbf(di * xs[2], 0.0f));
  *(uint2*)(xsb + (size_t)n * 2) = v;
}

// ---- graph segment boundaries ----
__global__ void k_bounds(const int* __restrict__ batch, int* __restrict__ start) {
  int g = blockIdx.x * blockDim.x + threadIdx.x;
  if (g > NUM_GRAPHS) return;
  int lo = 0, hi = N_NODES;
  while (lo < hi) { int mid = (lo + hi) >> 1; if (batch[mid] < g) lo = mid + 1; else hi = mid; }
  start[g] = lo;
}

// ---- layer 1 gather: 2 lanes/node, uint (2 bf16) per lane, unroll-2 ----
__global__ void k_gather1(const int* __restrict__ ssrc, const int* __restrict__ offs,
                          const unsigned* __restrict__ xsb, float* __restrict__ A1) {
  unsigned t = blockIdx.x * blockDim.x + threadIdx.x;
  unsigned n = t >> 1;
  int j = t & 1;
  if (n >= (unsigned)N_NODES) return;
  int o0 = offs[n], o1 = offs[n + 1];
  float a0 = 0.0f, a1 = 0.0f;
  int i = o0;
  for (; i + 1 < o1; i += 2) {
    int s0 = ssrc[i], s1 = ssrc[i + 1];
    unsigned q0 = xsb[(size_t)s0 * 2 + j];
    unsigned q1 = xsb[(size_t)s1 * 2 + j];
    a0 += bf_lo(q0) + bf_lo(q1);
    a1 += bf_hi(q0) + bf_hi(q1);
  }
  if (i < o1) {
    unsigned q = xsb[(size_t)ssrc[i] * 2 + j];
    a0 += bf_lo(q); a1 += bf_hi(q);
  }
  *(float2*)&A1[(size_t)n * 4 + 2 * j] = make_float2(a0, a1);
}

// ---- layer 1 finalize: u(bf16) = di * relu( (di*(A1+xs)) @ W1 + b1 ) ----
__global__ void k_fin1(const float* __restrict__ A1, const unsigned* __restrict__ xsb,
                       const float* __restrict__ dinv, const float* __restrict__ W1,
                       const float* __restrict__ b1, unsigned* __restrict__ ub) {
  unsigned t = blockIdx.x * blockDim.x + threadIdx.x;
  unsigned n = t >> 3;
  int h = t & 7;
  if (n >= (unsigned)N_NODES) return;
  float di = dinv[n];
  float4 a = *(const float4*)&A1[(size_t)n * 4];
  uint2 xq = *(const uint2*)&xsb[(size_t)n * 2];
  float t0 = di * (a.x + bf_lo(xq.x));
  float t1 = di * (a.y + bf_hi(xq.x));
  float t2 = di * (a.z + bf_lo(xq.y));
  int f = 2 * h;
  float v0 = t0 * W1[f]     + t1 * W1[16 + f]     + t2 * W1[32 + f]     + b1[f];
  float v1 = t0 * W1[f + 1] + t1 * W1[16 + f + 1] + t2 * W1[32 + f + 1] + b1[f + 1];
  ub[(size_t)n * 8 + h] = packbf(di * fmaxf(v0, 0.0f), di * fmaxf(v1, 0.0f));
}

// ---- layer 2 gather: 4 lanes/node, uint2 (4 bf16) per lane, unroll-2 ----
__global__ void k_gather2(const int* __restrict__ ssrc, const int* __restrict__ offs,
                          const unsigned* __restrict__ ub, float* __restrict__ A2) {
  unsigned t = blockIdx.x * blockDim.x + threadIdx.x;
  unsigned n = t >> 2;
  int j = t & 3;
  if (n >= (unsigned)N_NODES) return;
  int o0 = offs[n], o1 = offs[n + 1];
  float a0 = 0.0f, a1 = 0.0f, a2 = 0.0f, a3 = 0.0f;
  int i = o0;
  for (; i + 1 < o1; i += 2) {
    int s0 = ssrc[i], s1 = ssrc[i + 1];
    uint2 q0 = *(const uint2*)&ub[(size_t)s0 * 8 + j * 2];
    uint2 q1 = *(const uint2*)&ub[(size_t)s1 * 8 + j * 2];
    a0 += bf_lo(q0.x) + bf_lo(q1.x);
    a1 += bf_hi(q0.x) + bf_hi(q1.x);
    a2 += bf_lo(q0.y) + bf_lo(q1.y);
    a3 += bf_hi(q0.y) + bf_hi(q1.y);
  }
  if (i < o1) {
    uint2 q = *(const uint2*)&ub[(size_t)ssrc[i] * 8 + j * 2];
    a0 += bf_lo(q.x); a1 += bf_hi(q.x); a2 += bf_lo(q.y); a3 += bf_hi(q.y);
  }
  *(float4*)&A2[(size_t)n * 16 + j * 4] = make_float4(a0, a1, a2, a3);
}

// ---- pool v2: 128 contiguous nodes/block, 8 subgroups x 32 features ----
__global__ void k_pool2(const unsigned* __restrict__ ub, const float* __restrict__ A2,
                        const float* __restrict__ W2, const float* __restrict__ b2,
                        const float* __restrict__ dinv, const int* __restrict__ batch,
                        float* __restrict__ sums) {
  int f = threadIdx.x & 31, sub = threadIdx.x >> 5;
  int n0 = blockIdx.x * 128 + sub * 16;
  int n1 = min(n0 + 16, N_NODES);
  if (n0 >= n1) return;
  float w2col[16];
#pragma unroll
  for (int k = 0; k < 16; ++k) w2col[k] = W2[k * 32 + f];
  float bf = b2[f];
  int cur = batch[n0];
  float acc = 0.0f;
  for (int n = n0; n < n1; ++n) {
    int g = batch[n];
    if (g != cur) { atomicAdd(&sums[(size_t)cur * 32 + f], acc); acc = 0.0f; cur = g; }
    float di = dinv[n];
    const float4* a2p = (const float4*)(A2 + (size_t)n * 16);
    float4 aa0 = a2p[0], aa1 = a2p[1], aa2 = a2p[2], aa3 = a2p[3];
    const uint4* urp = (const uint4*)(ub + (size_t)n * 8);
    uint4 uq = urp[0], uq2 = urp[1];
    float un[16];
    un[0] = bf_lo(uq.x);  un[1] = bf_hi(uq.x);
    un[2] = bf_lo(uq.y);  un[3] = bf_hi(uq.y);
    un[4] = bf_lo(uq.z);  un[5] = bf_hi(uq.z);
    un[6] = bf_lo(uq.w);  un[7] = bf_hi(uq.w);
    un[8]  = bf_lo(uq2.x); un[9]  = bf_hi(uq2.x);
    un[10] = bf_lo(uq2.y); un[11] = bf_hi(uq2.y);
    un[12] = bf_lo(uq2.z); un[13] = bf_hi(uq2.z);
    un[14] = bf_lo(uq2.w); un[15] = bf_hi(uq2.w);
    float am[16] = {aa0.x, aa0.y, aa0.z, aa0.w, aa1.x, aa1.y, aa1.z, aa1.w,
                    aa2.x, aa2.y, aa2.z, aa2.w, aa3.x, aa3.y, aa3.z, aa3.w};
    float v = bf;
#pragma unroll
    for (int k = 0; k < 16; ++k) v += di * (am[k] + un[k]) * w2col[k];
    acc += fmaxf(v, 0.0f);
  }
  atomicAdd(&sums[(size_t)cur * 32 + f], acc);
}

// ---- final MLP + log_softmax (counts from gstart) ----
__global__ void k_mlp(const float* __restrict__ sums, const int* __restrict__ gstart,
                      const float* __restrict__ fW1, const float* __restrict__ fb1,
                      const float* __restrict__ fW2, const float* __restrict__ fb2,
                      float* __restrict__ out) {
  __shared__ float w1s[32 * 64];
  __shared__ float w2s[64 * 3];
  __shared__ float b1s[64];
  __shared__ float b2s[3];
  for (int i = threadIdx.x; i < 32 * 64; i += blockDim.x) w1s[i] = fW1[i];
  for (int i = threadIdx.x; i < 64 * 3; i += blockDim.x) w2s[i] = fW2[i];
  for (int i = threadIdx.x; i < 64; i += blockDim.x) b1s[i] = fb1[i];
  for (int i = threadIdx.x; i < 3; i += blockDim.x) b2s[i] = fb2[i];
  __syncthreads();
  int g = blockIdx.x * blockDim.x + threadIdx.x;
  if (g >= NUM_GRAPHS) return;
  float c = fmaxf((float)(gstart[g + 1] - gstart[g]), 1.0f);
  float p[32];
#pragma unroll
  for (int i = 0; i < 32; ++i) p[i] = sums[(size_t)g * 32 + i] / c;
  float z2[3] = {b2s[0], b2s[1], b2s[2]};
  for (int j = 0; j < 64; ++j) {
    float a = b1s[j];
#pragma unroll
    for (int i = 0; i < 32; ++i) a += p[i] * w1s[i * 64 + j];
    a = fmaxf(a, 0.0f);
#pragma unroll
    for (int k = 0; k < 3; ++k) z2[k] += a * w2s[j * 3 + k];
  }
  float m = fmaxf(fmaxf(z2[0], z2[1]), z2[2]);
  float l = logf(expf(z2[0] - m) + expf(z2[1] - m) + expf(z2[2] - m));
#pragma unroll
  for (int k = 0; k < 3; ++k) out[(size_t)g * 3 + k] = z2[k] - m - l;
}

extern "C" void kernel_launch(void* const* d_in, const int* in_sizes, int n_in,
                              void* d_out, int out_size, void* d_ws, size_t ws_size,
                              hipStream_t stream) {
  const float* x     = (const float*)d_in[0];
  const int*   ei    = (const int*)d_in[1];   // [2, E]
  const int*   batch = (const int*)d_in[2];
  const float* W1    = (const float*)d_in[3];
  const float* b1    = (const float*)d_in[4];
  const float* W2    = (const float*)d_in[5];
  const float* b2    = (const float*)d_in[6];
  const float* fW1   = (const float*)d_in[7];
  const float* fb1   = (const float*)d_in[8];
  const float* fW2   = (const float*)d_in[9];
  const float* fb2   = (const float*)d_in[10];
  const int* src = ei;
  const int* dst = ei + N_EDGES;

  // ---- workspace layout (≈99 MB) ----
  float* ws       = (float*)d_ws;
  float* dinv     = ws;                           // 524,288 f
  unsigned* xsb   = (unsigned*)(dinv + 524288);   // 1,048,576 u32 (2/node)
  unsigned* ub    = xsb + 1048576;                // 4,194,304 u32 (8/node)
  float* A1       = (float*)(ub + 4194304);       // 2,000,000 f (scan scratch aliased)
  float* sums     = A1 + 2000000;                 // 16384
  float* cntg     = sums + 16384;                 // 512 (unused, kept for layout)
  int* cnt        = (int*)(cntg + 512);           // 524,288
  int* offs       = cnt + 524288;                 // 524,288 (N_NODES+1 used)
  int* gstart     = offs + 524288;                // 1024 (513 used)
  int* ssrc       = gstart + 1024;                // 8,000,000
  int* pairs      = ssrc + 8000000;               // 8,000,000
  // aliases (dead ranges reused):
  int* H    = (int*)A1;                           // 262,144 (NH=240342 used)
  int* Sarr = H + 262144;                         // 262,144
  int* bsum = Sarr + 262144;                      // 1024 (NSB=939 used)
  float* A2 = (float*)pairs;                      // pairs dead after k_csr

  hipMemsetAsync(sums, 0, (size_t)NUM_GRAPHS * 32 * 4, stream);

  const int B = 256;
  k_hist<<<NBLK_A, B, 0, stream>>>(dst, H);
  k_scan1<<<NSB, SCAN_B, 0, stream>>>(H, Sarr, bsum, NH);
  k_scan2<<<1, SCAN_B, 0, stream>>>(bsum, NSB);
  k_scan3<<<(NH + B - 1) / B, B, 0, stream>>>(Sarr, bsum, NH);
  k_scatter_bkt<<<NBLK_A, B, 0, stream>>>(src, dst, Sarr, pairs);
  k_csr<<<NBKT, 1024, 0, stream>>>(pairs, Sarr, ssrc, cnt, offs);
  k_prep<<<(N_NODES + B - 1) / B, B, 0, stream>>>(cnt, x, dinv, xsb);
  k_bounds<<<(NUM_GRAPHS + 1 + B - 1) / B, B, 0, stream>>>(batch, gstart);
  k_gather1<<<((size_t)N_NODES * 2 + B - 1) / B, B, 0, stream>>>(ssrc, offs, xsb, A1);
  k_fin1<<<((size_t)N_NODES * 8 + B - 1) / B, B, 0, stream>>>(A1, xsb, dinv, W1, b1, ub);
  k_gather2<<<((size_t)N_NODES * 4 + B - 1) / B, B, 0, stream>>>(ssrc, offs, ub, A2);
  k_pool2<<<(N_NODES + 127) / 128, B, 0, stream>>>(ub, A2, W2, b2, dinv, batch, sums);
  k_mlp<<<(NUM_GRAPHS + B - 1) / B, B, 0, stream>>>(sums, gstart, fW1, fb1, fW2, fb2, (float*)d_out);
}

// Round 13
// 474.916 us; speedup vs baseline: 2.2964x; 1.0210x over previous
//
#include <hip/hip_runtime.h>
#include <hip/hip_bf16.h>

constexpr int N_NODES    = 500000;
constexpr int N_EDGES    = 8000000;
constexpr int NUM_GRAPHS = 512;

constexpr int BSHIFT = 11;                              // 2048 nodes / coarse bucket
constexpr int BSIZE  = 1 << BSHIFT;
constexpr int NBKT   = (N_NODES + BSIZE - 1) / BSIZE;   // 245
constexpr int EPB    = 4096;                            // edges per block (pass A)
constexpr int NBLK_A = (N_EDGES + EPB - 1) / EPB;       // 1954
constexpr int NH     = NBKT * NBLK_A;                   // 478,730
constexpr int SCAN_B = 256;
constexpr int NSB    = (NH + SCAN_B - 1) / SCAN_B;      // 1871

// ---- bf16 helpers (bit-level, RNE pack) ----
__device__ __forceinline__ float bf_lo(unsigned u) { return __uint_as_float(u << 16); }
__device__ __forceinline__ float bf_hi(unsigned u) { return __uint_as_float(u & 0xFFFF0000u); }
__device__ __forceinline__ unsigned short f2bf(float f) {
  unsigned u = __float_as_uint(f);
  return (unsigned short)((u + 0x7FFFu + ((u >> 16) & 1u)) >> 16);
}
__device__ __forceinline__ unsigned packbf(float a, float b) {
  return (unsigned)f2bf(a) | ((unsigned)f2bf(b) << 16);
}

// ---- pass A1: per-block coarse histogram (LDS atomics only) ----
__global__ void k_hist(const int* __restrict__ dst, int* __restrict__ H) {
  __shared__ int h[NBKT];
  for (int i = threadIdx.x; i < NBKT; i += blockDim.x) h[i] = 0;
  __syncthreads();
  int e0 = blockIdx.x * EPB;
  int e1 = min(e0 + EPB, N_EDGES);
  for (int e = e0 + threadIdx.x; e < e1; e += blockDim.x)
    atomicAdd(&h[dst[e] >> BSHIFT], 1);
  __syncthreads();
  for (int i = threadIdx.x; i < NBKT; i += blockDim.x)
    H[i * NBLK_A + blockIdx.x] = h[i];                  // bucket-major
}

// ---- exclusive scan of H (NH ints): 3 kernels ----
__global__ void k_scan1(const int* __restrict__ in, int* __restrict__ out,
                        int* __restrict__ bsum, int n) {
  __shared__ int tmp[SCAN_B];
  int t = threadIdx.x;
  int i = blockIdx.x * SCAN_B + t;
  int v = (i < n) ? in[i] : 0;
  tmp[t] = v;
  __syncthreads();
  for (int off = 1; off < SCAN_B; off <<= 1) {
    int a = (t >= off) ? tmp[t - off] : 0;
    __syncthreads();
    tmp[t] += a;
    __syncthreads();
  }
  if (i < n) out[i] = tmp[t] - v;
  if (t == SCAN_B - 1) bsum[blockIdx.x] = tmp[t];
}

__global__ void k_scan2(int* __restrict__ bsum, int nb) {  // in-place exclusive
  __shared__ int tmp[SCAN_B];
  int t = threadIdx.x;
  int carry = 0;
  for (int base = 0; base < nb; base += SCAN_B) {
    int i = base + t;
    int v = (i < nb) ? bsum[i] : 0;
    tmp[t] = v;
    __syncthreads();
    for (int off = 1; off < SCAN_B; off <<= 1) {
      int a = (t >= off) ? tmp[t - off] : 0;
      __syncthreads();
      tmp[t] += a;
      __syncthreads();
    }
    if (i < nb) bsum[i] = carry + tmp[t] - v;
    carry += tmp[SCAN_B - 1];
    __syncthreads();
  }
}

__global__ void k_scan3(int* __restrict__ out, const int* __restrict__ bsum, int n) {
  int i = blockIdx.x * blockDim.x + threadIdx.x;
  if (i < n) out[i] += bsum[i >> 8];
}

// ---- pass A3: block-local counting sort, then CONTIGUOUS per-bucket writes ----
__global__ void k_scatter_bkt(const int* __restrict__ src, const int* __restrict__ dst,
                              const int* __restrict__ S, int* __restrict__ pairs) {
  __shared__ int lcnt[256];            // per-bucket count, then reused as cursor
  __shared__ int lofs[256];            // exclusive local scan
  __shared__ int base[256];            // global base for (bucket, this block)
  __shared__ int pout[EPB];            // reordered pairs (16 KB)
  __shared__ unsigned char bout[EPB];  // bucket id per output slot (4 KB)
  int t = threadIdx.x;
  int blk = blockIdx.x;
  int e0 = blk * EPB;
  int e1 = min(e0 + EPB, N_EDGES);
  int ne = e1 - e0;
  lcnt[t] = 0;
  __syncthreads();
  // phase A: local histogram
  for (int e = e0 + t; e < e1; e += 256)
    atomicAdd(&lcnt[dst[e] >> BSHIFT], 1);
  __syncthreads();
  // exclusive scan over 256 bins (Hillis-Steele)
  lofs[t] = lcnt[t];
  __syncthreads();
  for (int off = 1; off < 256; off <<= 1) {
    int v = (t >= off) ? lofs[t - off] : 0;
    __syncthreads();
    lofs[t] += v;
    __syncthreads();
  }
  lofs[t] -= lcnt[t];                               // exclusive
  base[t] = (t < NBKT) ? S[t * NBLK_A + blk] : 0;   // global cursor base
  lcnt[t] = 0;                                      // reuse as local cursor
  __syncthreads();
  // phase B: rank + reorder into LDS
  for (int e = e0 + t; e < e1; e += 256) {
    int d = dst[e], s = src[e];
    int b = d >> BSHIFT;
    int r = atomicAdd(&lcnt[b], 1);
    int q = lofs[b] + r;
    pout[q] = ((d & (BSIZE - 1)) << 19) | s;        // s < 2^19, dlow 11 bits
    bout[q] = (unsigned char)b;                     // NBKT=245 <= 255
  }
  __syncthreads();
  // phase C: contiguous global writes per bucket run
  for (int li = t; li < ne; li += 256) {
    int b = bout[li];
    pairs[base[b] + (li - lofs[b])] = pout[li];
  }
}

// ---- pass B: per-bucket CSR finalize (one block per bucket, 1024 thr, 2 nodes/thr) ----
__global__ void __launch_bounds__(1024)
k_csr(const int* __restrict__ pairs, const int* __restrict__ S,
      int* __restrict__ ssrc, int* __restrict__ cnt, int* __restrict__ offs) {
  __shared__ int hist[BSIZE];          // 2048 bins, 8 KB
  __shared__ int tmp[1024];
  int t = threadIdx.x;
  int bkt = blockIdx.x;
  int n0 = bkt << BSHIFT;
  int e0 = S[bkt * NBLK_A];
  int e1 = (bkt + 1 < NBKT) ? S[(bkt + 1) * NBLK_A] : N_EDGES;
  hist[t] = 0; hist[t + 1024] = 0;
  __syncthreads();
  for (int e = e0 + t; e < e1; e += 1024)
    atomicAdd(&hist[pairs[e] >> 19], 1);
  __syncthreads();
  int c0 = hist[2 * t], c1 = hist[2 * t + 1];
  int tsum = c0 + c1;
  tmp[t] = tsum;
  __syncthreads();
  for (int off = 1; off < 1024; off <<= 1) {
    int a = (t >= off) ? tmp[t - off] : 0;
    __syncthreads();
    tmp[t] += a;
    __syncthreads();
  }
  int tbase = tmp[t] - tsum;           // exclusive over threads
  hist[2 * t] = tbase; hist[2 * t + 1] = tbase + c0;
  int n = n0 + 2 * t;
  if (n < N_NODES)     { cnt[n]     = c0; offs[n]     = e0 + tbase; }
  if (n + 1 < N_NODES) { cnt[n + 1] = c1; offs[n + 1] = e0 + tbase + c0; }
  __syncthreads();
  for (int e = e0 + t; e < e1; e += 1024) {
    int p = pairs[e];
    int r = atomicAdd(&hist[p >> 19], 1);
    ssrc[e0 + r] = p & 0x7FFFF;
  }
  if (bkt == 0 && t == 0) offs[N_NODES] = N_EDGES;
}

// ---- dinv + pre-scaled bf16 features: xsb[n] = {bf(di*x0), bf(di*x1), bf(di*x2), 0} ----
__global__ void k_prep(const int* __restrict__ cnt, const float* __restrict__ x,
                       float* __restrict__ dinv, unsigned* __restrict__ xsb) {
  int n = blockIdx.x * blockDim.x + threadIdx.x;
  if (n >= N_NODES) return;
  float di = rsqrtf((float)cnt[n] + 1.0f);
  dinv[n] = di;
  const float* xs = x + (size_t)n * 3;
  uint2 v = make_uint2(packbf(di * xs[0], di * xs[1]), packbf(di * xs[2], 0.0f));
  *(uint2*)(xsb + (size_t)n * 2) = v;
}

// ---- graph segment boundaries ----
__global__ void k_bounds(const int* __restrict__ batch, int* __restrict__ start) {
  int g = blockIdx.x * blockDim.x + threadIdx.x;
  if (g > NUM_GRAPHS) return;
  int lo = 0, hi = N_NODES;
  while (lo < hi) { int mid = (lo + hi) >> 1; if (batch[mid] < g) lo = mid + 1; else hi = mid; }
  start[g] = lo;
}

// ---- FUSED layer-1 gather + finalize: 2 lanes/node, shfl pair-exchange, no A1 ----
// j=0 accumulates (A0,A1); j=1 accumulates (A2,pad). After shfl_xor(1) both lanes
// hold all three sums; each computes 8 of 16 output features -> one uint4 store.
__global__ void k_g1f1(const int* __restrict__ ssrc, const int* __restrict__ offs,
                       const unsigned* __restrict__ xsb, const float* __restrict__ dinv,
                       const float* __restrict__ W1, const float* __restrict__ b1,
                       unsigned* __restrict__ ub) {
  unsigned t = blockIdx.x * blockDim.x + threadIdx.x;
  unsigned n = t >> 1;
  int j = t & 1;
  if (n >= (unsigned)N_NODES) return;
  int o0 = offs[n], o1 = offs[n + 1];
  float a0 = 0.0f, a1 = 0.0f;
  int i = o0;
  for (; i + 1 < o1; i += 2) {
    int s0 = ssrc[i], s1 = ssrc[i + 1];
    unsigned q0 = xsb[(size_t)s0 * 2 + j];
    unsigned q1 = xsb[(size_t)s1 * 2 + j];
    a0 += bf_lo(q0) + bf_lo(q1);
    a1 += bf_hi(q0) + bf_hi(q1);
  }
  if (i < o1) {
    unsigned q = xsb[(size_t)ssrc[i] * 2 + j];
    a0 += bf_lo(q); a1 += bf_hi(q);
  }
  // pair exchange (lanes t and t^1 share node n)
  float oth0 = __shfl_xor(a0, 1);
  float oth1 = __shfl_xor(a1, 1);
  float A0 = j ? oth0 : a0;
  float A1v = j ? oth1 : a1;
  float A2v = j ? a0 : oth0;
  float di = dinv[n];
  uint2 xq = *(const uint2*)&xsb[(size_t)n * 2];
  float t0 = di * (A0 + bf_lo(xq.x));
  float t1 = di * (A1v + bf_hi(xq.x));
  float t2 = di * (A2v + bf_lo(xq.y));
  unsigned outv[4];
#pragma unroll
  for (int q8 = 0; q8 < 4; ++q8) {
    int f = 8 * j + 2 * q8;
    float v0 = t0 * W1[f]     + t1 * W1[16 + f]     + t2 * W1[32 + f]     + b1[f];
    float v1 = t0 * W1[f + 1] + t1 * W1[16 + f + 1] + t2 * W1[32 + f + 1] + b1[f + 1];
    outv[q8] = packbf(di * fmaxf(v0, 0.0f), di * fmaxf(v1, 0.0f));
  }
  *(uint4*)&ub[(size_t)n * 8 + j * 4] = make_uint4(outv[0], outv[1], outv[2], outv[3]);
}

// ---- layer 2 gather: 4 lanes/node, uint2 (4 bf16) per lane, unroll-2 ----
__global__ void k_gather2(const int* __restrict__ ssrc, const int* __restrict__ offs,
                          const unsigned* __restrict__ ub, float* __restrict__ A2) {
  unsigned t = blockIdx.x * blockDim.x + threadIdx.x;
  unsigned n = t >> 2;
  int j = t & 3;
  if (n >= (unsigned)N_NODES) return;
  int o0 = offs[n], o1 = offs[n + 1];
  float a0 = 0.0f, a1 = 0.0f, a2 = 0.0f, a3 = 0.0f;
  int i = o0;
  for (; i + 1 < o1; i += 2) {
    int s0 = ssrc[i], s1 = ssrc[i + 1];
    uint2 q0 = *(const uint2*)&ub[(size_t)s0 * 8 + j * 2];
    uint2 q1 = *(const uint2*)&ub[(size_t)s1 * 8 + j * 2];
    a0 += bf_lo(q0.x) + bf_lo(q1.x);
    a1 += bf_hi(q0.x) + bf_hi(q1.x);
    a2 += bf_lo(q0.y) + bf_lo(q1.y);
    a3 += bf_hi(q0.y) + bf_hi(q1.y);
  }
  if (i < o1) {
    uint2 q = *(const uint2*)&ub[(size_t)ssrc[i] * 8 + j * 2];
    a0 += bf_lo(q.x); a1 += bf_hi(q.x); a2 += bf_lo(q.y); a3 += bf_hi(q.y);
  }
  *(float4*)&A2[(size_t)n * 16 + j * 4] = make_float4(a0, a1, a2, a3);
}

// ---- pool v2: 128 contiguous nodes/block, 8 subgroups x 32 features ----
__global__ void k_pool2(const unsigned* __restrict__ ub, const float* __restrict__ A2,
                        const float* __restrict__ W2, const float* __restrict__ b2,
                        const float* __restrict__ dinv, const int* __restrict__ batch,
                        float* __restrict__ sums) {
  int f = threadIdx.x & 31, sub = threadIdx.x >> 5;
  int n0 = blockIdx.x * 128 + sub * 16;
  int n1 = min(n0 + 16, N_NODES);
  if (n0 >= n1) return;
  float w2col[16];
#pragma unroll
  for (int k = 0; k < 16; ++k) w2col[k] = W2[k * 32 + f];
  float bf = b2[f];
  int cur = batch[n0];
  float acc = 0.0f;
  for (int n = n0; n < n1; ++n) {
    int g = batch[n];
    if (g != cur) { atomicAdd(&sums[(size_t)cur * 32 + f], acc); acc = 0.0f; cur = g; }
    float di = dinv[n];
    const float4* a2p = (const float4*)(A2 + (size_t)n * 16);
    float4 aa0 = a2p[0], aa1 = a2p[1], aa2 = a2p[2], aa3 = a2p[3];
    const uint4* urp = (const uint4*)(ub + (size_t)n * 8);
    uint4 uq = urp[0], uq2 = urp[1];
    float un[16];
    un[0] = bf_lo(uq.x);  un[1] = bf_hi(uq.x);
    un[2] = bf_lo(uq.y);  un[3] = bf_hi(uq.y);
    un[4] = bf_lo(uq.z);  un[5] = bf_hi(uq.z);
    un[6] = bf_lo(uq.w);  un[7] = bf_hi(uq.w);
    un[8]  = bf_lo(uq2.x); un[9]  = bf_hi(uq2.x);
    un[10] = bf_lo(uq2.y); un[11] = bf_hi(uq2.y);
    un[12] = bf_lo(uq2.z); un[13] = bf_hi(uq2.z);
    un[14] = bf_lo(uq2.w); un[15] = bf_hi(uq2.w);
    float am[16] = {aa0.x, aa0.y, aa0.z, aa0.w, aa1.x, aa1.y, aa1.z, aa1.w,
                    aa2.x, aa2.y, aa2.z, aa2.w, aa3.x, aa3.y, aa3.z, aa3.w};
    float v = bf;
#pragma unroll
    for (int k = 0; k < 16; ++k) v += di * (am[k] + un[k]) * w2col[k];
    acc += fmaxf(v, 0.0f);
  }
  atomicAdd(&sums[(size_t)cur * 32 + f], acc);
}

// ---- final MLP + log_softmax (counts from gstart) ----
__global__ void k_mlp(const float* __restrict__ sums, const int* __restrict__ gstart,
                      const float* __restrict__ fW1, const float* __restrict__ fb1,
                      const float* __restrict__ fW2, const float* __restrict__ fb2,
                      float* __restrict__ out) {
  __shared__ float w1s[32 * 64];
  __shared__ float w2s[64 * 3];
  __shared__ float b1s[64];
  __shared__ float b2s[3];
  for (int i = threadIdx.x; i < 32 * 64; i += blockDim.x) w1s[i] = fW1[i];
  for (int i = threadIdx.x; i < 64 * 3; i += blockDim.x) w2s[i] = fW2[i];
  for (int i = threadIdx.x; i < 64; i += blockDim.x) b1s[i] = fb1[i];
  for (int i = threadIdx.x; i < 3; i += blockDim.x) b2s[i] = fb2[i];
  __syncthreads();
  int g = blockIdx.x * blockDim.x + threadIdx.x;
  if (g >= NUM_GRAPHS) return;
  float c = fmaxf((float)(gstart[g + 1] - gstart[g]), 1.0f);
  float p[32];
#pragma unroll
  for (int i = 0; i < 32; ++i) p[i] = sums[(size_t)g * 32 + i] / c;
  float z2[3] = {b2s[0], b2s[1], b2s[2]};
  for (int j = 0; j < 64; ++j) {
    float a = b1s[j];
#pragma unroll
    for (int i = 0; i < 32; ++i) a += p[i] * w1s[i * 64 + j];
    a = fmaxf(a, 0.0f);
#pragma unroll
    for (int k = 0; k < 3; ++k) z2[k] += a * w2s[j * 3 + k];
  }
  float m = fmaxf(fmaxf(z2[0], z2[1]), z2[2]);
  float l = logf(expf(z2[0] - m) + expf(z2[1] - m) + expf(z2[2] - m));
#pragma unroll
  for (int k = 0; k < 3; ++k) out[(size_t)g * 3 + k] = z2[k] - m - l;
}

extern "C" void kernel_launch(void* const* d_in, const int* in_sizes, int n_in,
                              void* d_out, int out_size, void* d_ws, size_t ws_size,
                              hipStream_t stream) {
  const float* x     = (const float*)d_in[0];
  const int*   ei    = (const int*)d_in[1];   // [2, E]
  const int*   batch = (const int*)d_in[2];
  const float* W1    = (const float*)d_in[3];
  const float* b1    = (const float*)d_in[4];
  const float* W2    = (const float*)d_in[5];
  const float* b2    = (const float*)d_in[6];
  const float* fW1   = (const float*)d_in[7];
  const float* fb1   = (const float*)d_in[8];
  const float* fW2   = (const float*)d_in[9];
  const float* fb2   = (const float*)d_in[10];
  const int* src = ei;
  const int* dst = ei + N_EDGES;

  // ---- workspace layout (≈99 MB) ----
  float* ws       = (float*)d_ws;
  float* dinv     = ws;                           // 524,288 f
  unsigned* xsb   = (unsigned*)(dinv + 524288);   // 1,048,576 u32 (2/node)
  unsigned* ub    = xsb + 1048576;                // 4,194,304 u32 (8/node)
  float* scratch  = (float*)(ub + 4194304);       // 2,000,000 f (scan scratch)
  float* sums     = scratch + 2000000;            // 16384
  float* cntg     = sums + 16384;                 // 512 (unused, kept for layout)
  int* cnt        = (int*)(cntg + 512);           // 524,288
  int* offs       = cnt + 524288;                 // 524,288 (N_NODES+1 used)
  int* gstart     = offs + 524288;                // 1024 (513 used)
  int* ssrc       = gstart + 1024;                // 8,000,000
  int* pairs      = ssrc + 8000000;               // 8,000,000
  // aliases (dead ranges reused):
  int* H    = (int*)scratch;                      // NH = 478,730
  int* Sarr = H + 478730;                         // 478,730
  int* bsum = Sarr + 478730;                      // 1871  (total 959,331 < 2,000,000)
  float* A2 = (float*)pairs;                      // pairs dead after k_csr

  hipMemsetAsync(sums, 0, (size_t)NUM_GRAPHS * 32 * 4, stream);

  const int B = 256;
  k_hist<<<NBLK_A, B, 0, stream>>>(dst, H);
  k_scan1<<<NSB, SCAN_B, 0, stream>>>(H, Sarr, bsum, NH);
  k_scan2<<<1, SCAN_B, 0, stream>>>(bsum, NSB);
  k_scan3<<<(NH + B - 1) / B, B, 0, stream>>>(Sarr, bsum, NH);
  k_scatter_bkt<<<NBLK_A, B, 0, stream>>>(src, dst, Sarr, pairs);
  k_csr<<<NBKT, 1024, 0, stream>>>(pairs, Sarr, ssrc, cnt, offs);
  k_prep<<<(N_NODES + B - 1) / B, B, 0, stream>>>(cnt, x, dinv, xsb);
  k_bounds<<<(NUM_GRAPHS + 1 + B - 1) / B, B, 0, stream>>>(batch, gstart);
  k_g1f1<<<((size_t)N_NODES * 2 + B - 1) / B, B, 0, stream>>>(ssrc, offs, xsb, dinv, W1, b1, ub);
  k_gather2<<<((size_t)N_NODES * 4 + B - 1) / B, B, 0, stream>>>(ssrc, offs, ub, A2);
  k_pool2<<<(N_NODES + 127) / 128, B, 0, stream>>>(ub, A2, W2, b2, dinv, batch, sums);
  k_mlp<<<(NUM_GRAPHS + B - 1) / B, B, 0, stream>>>(sums, gstart, fW1, fb1, fW2, fb2, (float*)d_out);
}

// Round 14
// 474.032 us; speedup vs baseline: 2.3007x; 1.0019x over previous
//
#include <hip/hip_runtime.h>
#include <hip/hip_bf16.h>

constexpr int N_NODES    = 500000;
constexpr int N_EDGES    = 8000000;
constexpr int NUM_GRAPHS = 512;

constexpr int BSHIFT = 11;                              // 2048 nodes / coarse bucket
constexpr int BSIZE  = 1 << BSHIFT;
constexpr int NBKT   = (N_NODES + BSIZE - 1) / BSIZE;   // 245
constexpr int EPB    = 4096;                            // edges per block (pass A)
constexpr int NBLK_A = (N_EDGES + EPB - 1) / EPB;       // 1954
constexpr int NH     = NBKT * NBLK_A;                   // 478,730
constexpr int SCAN_B = 256;
constexpr int NSB    = (NH + SCAN_B - 1) / SCAN_B;      // 1871

// ---- bf16 helpers (bit-level, RNE pack) ----
__device__ __forceinline__ float bf_lo(unsigned u) { return __uint_as_float(u << 16); }
__device__ __forceinline__ float bf_hi(unsigned u) { return __uint_as_float(u & 0xFFFF0000u); }
__device__ __forceinline__ unsigned short f2bf(float f) {
  unsigned u = __float_as_uint(f);
  return (unsigned short)((u + 0x7FFFu + ((u >> 16) & 1u)) >> 16);
}
__device__ __forceinline__ unsigned packbf(float a, float b) {
  return (unsigned)f2bf(a) | ((unsigned)f2bf(b) << 16);
}

// ---- pass A1: per-block coarse histogram (LDS atomics only) ----
__global__ void k_hist(const int* __restrict__ dst, int* __restrict__ H) {
  __shared__ int h[NBKT];
  for (int i = threadIdx.x; i < NBKT; i += blockDim.x) h[i] = 0;
  __syncthreads();
  int e0 = blockIdx.x * EPB;
  int e1 = min(e0 + EPB, N_EDGES);
  for (int e = e0 + threadIdx.x; e < e1; e += blockDim.x)
    atomicAdd(&h[dst[e] >> BSHIFT], 1);
  __syncthreads();
  for (int i = threadIdx.x; i < NBKT; i += blockDim.x)
    H[i * NBLK_A + blockIdx.x] = h[i];                  // bucket-major
}

// ---- exclusive scan of H: 2 kernels (scan3 folded into consumers) ----
__global__ void k_scan1(const int* __restrict__ in, int* __restrict__ out,
                        int* __restrict__ bsum, int n) {
  __shared__ int tmp[SCAN_B];
  int t = threadIdx.x;
  int i = blockIdx.x * SCAN_B + t;
  int v = (i < n) ? in[i] : 0;
  tmp[t] = v;
  __syncthreads();
  for (int off = 1; off < SCAN_B; off <<= 1) {
    int a = (t >= off) ? tmp[t - off] : 0;
    __syncthreads();
    tmp[t] += a;
    __syncthreads();
  }
  if (i < n) out[i] = tmp[t] - v;
  if (t == SCAN_B - 1) bsum[blockIdx.x] = tmp[t];
}

__global__ void k_scan2(int* __restrict__ bsum, int nb) {  // in-place exclusive
  __shared__ int tmp[SCAN_B];
  int t = threadIdx.x;
  int carry = 0;
  for (int base = 0; base < nb; base += SCAN_B) {
    int i = base + t;
    int v = (i < nb) ? bsum[i] : 0;
    tmp[t] = v;
    __syncthreads();
    for (int off = 1; off < SCAN_B; off <<= 1) {
      int a = (t >= off) ? tmp[t - off] : 0;
      __syncthreads();
      tmp[t] += a;
      __syncthreads();
    }
    if (i < nb) bsum[i] = carry + tmp[t] - v;
    carry += tmp[SCAN_B - 1];
    __syncthreads();
  }
}

// S(idx) = Sarr[idx] + bsum[idx>>8]  (scan3 inlined)
__device__ __forceinline__ int s_at(const int* Sarr, const int* bsum, int idx) {
  return Sarr[idx] + bsum[idx >> 8];
}

// ---- pass A3: block-local counting sort, then CONTIGUOUS per-bucket writes ----
__global__ void k_scatter_bkt(const int* __restrict__ src, const int* __restrict__ dst,
                              const int* __restrict__ Sarr, const int* __restrict__ bsum,
                              int* __restrict__ pairs) {
  __shared__ int lcnt[256];            // per-bucket count, then reused as cursor
  __shared__ int lofs[256];            // exclusive local scan
  __shared__ int base[256];            // global base for (bucket, this block)
  __shared__ int pout[EPB];            // reordered pairs (16 KB)
  __shared__ unsigned char bout[EPB];  // bucket id per output slot (4 KB)
  int t = threadIdx.x;
  int blk = blockIdx.x;
  int e0 = blk * EPB;
  int e1 = min(e0 + EPB, N_EDGES);
  int ne = e1 - e0;
  lcnt[t] = 0;
  __syncthreads();
  for (int e = e0 + t; e < e1; e += 256)
    atomicAdd(&lcnt[dst[e] >> BSHIFT], 1);
  __syncthreads();
  lofs[t] = lcnt[t];
  __syncthreads();
  for (int off = 1; off < 256; off <<= 1) {
    int v = (t >= off) ? lofs[t - off] : 0;
    __syncthreads();
    lofs[t] += v;
    __syncthreads();
  }
  lofs[t] -= lcnt[t];                               // exclusive
  base[t] = (t < NBKT) ? s_at(Sarr, bsum, t * NBLK_A + blk) : 0;
  lcnt[t] = 0;                                      // reuse as local cursor
  __syncthreads();
  for (int e = e0 + t; e < e1; e += 256) {
    int d = dst[e], s = src[e];
    int b = d >> BSHIFT;
    int r = atomicAdd(&lcnt[b], 1);
    int q = lofs[b] + r;
    pout[q] = ((d & (BSIZE - 1)) << 19) | s;        // s < 2^19, dlow 11 bits
    bout[q] = (unsigned char)b;                     // NBKT=245 <= 255
  }
  __syncthreads();
  for (int li = t; li < ne; li += 256) {
    int b = bout[li];
    pairs[base[b] + (li - lofs[b])] = pout[li];
  }
}

// ---- pass B: per-bucket CSR finalize + FUSED prep (dinv, xsb) ----
__global__ void __launch_bounds__(1024)
k_csr(const int* __restrict__ pairs, const int* __restrict__ Sarr,
      const int* __restrict__ bsum, const float* __restrict__ x,
      int* __restrict__ ssrc, int* __restrict__ offs,
      float* __restrict__ dinv, unsigned* __restrict__ xsb) {
  __shared__ int hist[BSIZE];          // 2048 bins, 8 KB
  __shared__ int tmp[1024];
  int t = threadIdx.x;
  int bkt = blockIdx.x;
  int n0 = bkt << BSHIFT;
  int e0 = s_at(Sarr, bsum, bkt * NBLK_A);
  int e1 = (bkt + 1 < NBKT) ? s_at(Sarr, bsum, (bkt + 1) * NBLK_A) : N_EDGES;
  hist[t] = 0; hist[t + 1024] = 0;
  __syncthreads();
  for (int e = e0 + t; e < e1; e += 1024)
    atomicAdd(&hist[pairs[e] >> 19], 1);
  __syncthreads();
  int c0 = hist[2 * t], c1 = hist[2 * t + 1];
  int tsum = c0 + c1;
  tmp[t] = tsum;
  __syncthreads();
  for (int off = 1; off < 1024; off <<= 1) {
    int a = (t >= off) ? tmp[t - off] : 0;
    __syncthreads();
    tmp[t] += a;
    __syncthreads();
  }
  int tbase = tmp[t] - tsum;           // exclusive over threads
  hist[2 * t] = tbase; hist[2 * t + 1] = tbase + c0;
  int n = n0 + 2 * t;
  if (n < N_NODES) {
    offs[n] = e0 + tbase;
    float di = rsqrtf((float)c0 + 1.0f);
    dinv[n] = di;
    const float* xs = x + (size_t)n * 3;
    uint2 v = make_uint2(packbf(di * xs[0], di * xs[1]), packbf(di * xs[2], 0.0f));
    *(uint2*)(xsb + (size_t)n * 2) = v;
  }
  if (n + 1 < N_NODES) {
    offs[n + 1] = e0 + tbase + c0;
    float di = rsqrtf((float)c1 + 1.0f);
    dinv[n + 1] = di;
    const float* xs = x + (size_t)(n + 1) * 3;
    uint2 v = make_uint2(packbf(di * xs[0], di * xs[1]), packbf(di * xs[2], 0.0f));
    *(uint2*)(xsb + (size_t)(n + 1) * 2) = v;
  }
  __syncthreads();
  for (int e = e0 + t; e < e1; e += 1024) {
    int p = pairs[e];
    int r = atomicAdd(&hist[p >> 19], 1);
    ssrc[e0 + r] = p & 0x7FFFF;
  }
  if (bkt == 0 && t == 0) offs[N_NODES] = N_EDGES;
}

// ---- FUSED layer-1 gather + finalize: 2 lanes/node, shfl pair-exchange ----
__global__ void k_g1f1(const int* __restrict__ ssrc, const int* __restrict__ offs,
                       const unsigned* __restrict__ xsb, const float* __restrict__ dinv,
                       const float* __restrict__ W1, const float* __restrict__ b1,
                       unsigned* __restrict__ ub) {
  unsigned t = blockIdx.x * blockDim.x + threadIdx.x;
  unsigned n = t >> 1;
  int j = t & 1;
  if (n >= (unsigned)N_NODES) return;
  int o0 = offs[n], o1 = offs[n + 1];
  float a0 = 0.0f, a1 = 0.0f;
  int i = o0;
  for (; i + 1 < o1; i += 2) {
    int s0 = ssrc[i], s1 = ssrc[i + 1];
    unsigned q0 = xsb[(size_t)s0 * 2 + j];
    unsigned q1 = xsb[(size_t)s1 * 2 + j];
    a0 += bf_lo(q0) + bf_lo(q1);
    a1 += bf_hi(q0) + bf_hi(q1);
  }
  if (i < o1) {
    unsigned q = xsb[(size_t)ssrc[i] * 2 + j];
    a0 += bf_lo(q); a1 += bf_hi(q);
  }
  float oth0 = __shfl_xor(a0, 1);
  float oth1 = __shfl_xor(a1, 1);
  float A0 = j ? oth0 : a0;
  float A1v = j ? oth1 : a1;
  float A2v = j ? a0 : oth0;
  float di = dinv[n];
  uint2 xq = *(const uint2*)&xsb[(size_t)n * 2];
  float t0 = di * (A0 + bf_lo(xq.x));
  float t1 = di * (A1v + bf_hi(xq.x));
  float t2 = di * (A2v + bf_lo(xq.y));
  unsigned outv[4];
#pragma unroll
  for (int q8 = 0; q8 < 4; ++q8) {
    int f = 8 * j + 2 * q8;
    float v0 = t0 * W1[f]     + t1 * W1[16 + f]     + t2 * W1[32 + f]     + b1[f];
    float v1 = t0 * W1[f + 1] + t1 * W1[16 + f + 1] + t2 * W1[32 + f + 1] + b1[f + 1];
    outv[q8] = packbf(di * fmaxf(v0, 0.0f), di * fmaxf(v1, 0.0f));
  }
  *(uint4*)&ub[(size_t)n * 8 + j * 4] = make_uint4(outv[0], outv[1], outv[2], outv[3]);
}

// ---- layer 2 gather: 4 lanes/node, uint2 (4 bf16) per lane, unroll-2 ----
__global__ void k_gather2(const int* __restrict__ ssrc, const int* __restrict__ offs,
                          const unsigned* __restrict__ ub, float* __restrict__ A2) {
  unsigned t = blockIdx.x * blockDim.x + threadIdx.x;
  unsigned n = t >> 2;
  int j = t & 3;
  if (n >= (unsigned)N_NODES) return;
  int o0 = offs[n], o1 = offs[n + 1];
  float a0 = 0.0f, a1 = 0.0f, a2 = 0.0f, a3 = 0.0f;
  int i = o0;
  for (; i + 1 < o1; i += 2) {
    int s0 = ssrc[i], s1 = ssrc[i + 1];
    uint2 q0 = *(const uint2*)&ub[(size_t)s0 * 8 + j * 2];
    uint2 q1 = *(const uint2*)&ub[(size_t)s1 * 8 + j * 2];
    a0 += bf_lo(q0.x) + bf_lo(q1.x);
    a1 += bf_hi(q0.x) + bf_hi(q1.x);
    a2 += bf_lo(q0.y) + bf_lo(q1.y);
    a3 += bf_hi(q0.y) + bf_hi(q1.y);
  }
  if (i < o1) {
    uint2 q = *(const uint2*)&ub[(size_t)ssrc[i] * 8 + j * 2];
    a0 += bf_lo(q.x); a1 += bf_hi(q.x); a2 += bf_lo(q.y); a3 += bf_hi(q.y);
  }
  *(float4*)&A2[(size_t)n * 16 + j * 4] = make_float4(a0, a1, a2, a3);
}

// ---- pool v2: 128 contiguous nodes/block, 8 subgroups x 32 features ----
__global__ void k_pool2(const unsigned* __restrict__ ub, const float* __restrict__ A2,
                        const float* __restrict__ W2, const float* __restrict__ b2,
                        const float* __restrict__ dinv, const int* __restrict__ batch,
                        float* __restrict__ sums) {
  int f = threadIdx.x & 31, sub = threadIdx.x >> 5;
  int n0 = blockIdx.x * 128 + sub * 16;
  int n1 = min(n0 + 16, N_NODES);
  if (n0 >= n1) return;
  float w2col[16];
#pragma unroll
  for (int k = 0; k < 16; ++k) w2col[k] = W2[k * 32 + f];
  float bf = b2[f];
  int cur = batch[n0];
  float acc = 0.0f;
  for (int n = n0; n < n1; ++n) {
    int g = batch[n];
    if (g != cur) { atomicAdd(&sums[(size_t)cur * 32 + f], acc); acc = 0.0f; cur = g; }
    float di = dinv[n];
    const float4* a2p = (const float4*)(A2 + (size_t)n * 16);
    float4 aa0 = a2p[0], aa1 = a2p[1], aa2 = a2p[2], aa3 = a2p[3];
    const uint4* urp = (const uint4*)(ub + (size_t)n * 8);
    uint4 uq = urp[0], uq2 = urp[1];
    float un[16];
    un[0] = bf_lo(uq.x);  un[1] = bf_hi(uq.x);
    un[2] = bf_lo(uq.y);  un[3] = bf_hi(uq.y);
    un[4] = bf_lo(uq.z);  un[5] = bf_hi(uq.z);
    un[6] = bf_lo(uq.w);  un[7] = bf_hi(uq.w);
    un[8]  = bf_lo(uq2.x); un[9]  = bf_hi(uq2.x);
    un[10] = bf_lo(uq2.y); un[11] = bf_hi(uq2.y);
    un[12] = bf_lo(uq2.z); un[13] = bf_hi(uq2.z);
    un[14] = bf_lo(uq2.w); un[15] = bf_hi(uq2.w);
    float am[16] = {aa0.x, aa0.y, aa0.z, aa0.w, aa1.x, aa1.y, aa1.z, aa1.w,
                    aa2.x, aa2.y, aa2.z, aa2.w, aa3.x, aa3.y, aa3.z, aa3.w};
    float v = bf;
#pragma unroll
    for (int k = 0; k < 16; ++k) v += di * (am[k] + un[k]) * w2col[k];
    acc += fmaxf(v, 0.0f);
  }
  atomicAdd(&sums[(size_t)cur * 32 + f], acc);
}

// ---- final MLP + log_softmax, with FUSED segment bounds (binary search) ----
__global__ void k_mlp(const float* __restrict__ sums, const int* __restrict__ batch,
                      const float* __restrict__ fW1, const float* __restrict__ fb1,
                      const float* __restrict__ fW2, const float* __restrict__ fb2,
                      float* __restrict__ out) {
  __shared__ float w1s[32 * 64];
  __shared__ float w2s[64 * 3];
  __shared__ float b1s[64];
  __shared__ float b2s[3];
  for (int i = threadIdx.x; i < 32 * 64; i += blockDim.x) w1s[i] = fW1[i];
  for (int i = threadIdx.x; i < 64 * 3; i += blockDim.x) w2s[i] = fW2[i];
  for (int i = threadIdx.x; i < 64; i += blockDim.x) b1s[i] = fb1[i];
  for (int i = threadIdx.x; i < 3; i += blockDim.x) b2s[i] = fb2[i];
  __syncthreads();
  int g = blockIdx.x * blockDim.x + threadIdx.x;
  if (g >= NUM_GRAPHS) return;
  int lo = 0, hi = N_NODES;
  while (lo < hi) { int mid = (lo + hi) >> 1; if (batch[mid] < g) lo = mid + 1; else hi = mid; }
  int s0 = lo;
  int lo2 = s0, hi2 = N_NODES;
  while (lo2 < hi2) { int mid = (lo2 + hi2) >> 1; if (batch[mid] < g + 1) lo2 = mid + 1; else hi2 = mid; }
  float c = fmaxf((float)(lo2 - s0), 1.0f);
  float p[32];
#pragma unroll
  for (int i = 0; i < 32; ++i) p[i] = sums[(size_t)g * 32 + i] / c;
  float z2[3] = {b2s[0], b2s[1], b2s[2]};
  for (int j = 0; j < 64; ++j) {
    float a = b1s[j];
#pragma unroll
    for (int i = 0; i < 32; ++i) a += p[i] * w1s[i * 64 + j];
    a = fmaxf(a, 0.0f);
#pragma unroll
    for (int k = 0; k < 3; ++k) z2[k] += a * w2s[j * 3 + k];
  }
  float m = fmaxf(fmaxf(z2[0], z2[1]), z2[2]);
  float l = logf(expf(z2[0] - m) + expf(z2[1] - m) + expf(z2[2] - m));
#pragma unroll
  for (int k = 0; k < 3; ++k) out[(size_t)g * 3 + k] = z2[k] - m - l;
}

extern "C" void kernel_launch(void* const* d_in, const int* in_sizes, int n_in,
                              void* d_out, int out_size, void* d_ws, size_t ws_size,
                              hipStream_t stream) {
  const float* x     = (const float*)d_in[0];
  const int*   ei    = (const int*)d_in[1];   // [2, E]
  const int*   batch = (const int*)d_in[2];
  const float* W1    = (const float*)d_in[3];
  const float* b1    = (const float*)d_in[4];
  const float* W2    = (const float*)d_in[5];
  const float* b2    = (const float*)d_in[6];
  const float* fW1   = (const float*)d_in[7];
  const float* fb1   = (const float*)d_in[8];
  const float* fW2   = (const float*)d_in[9];
  const float* fb2   = (const float*)d_in[10];
  const int* src = ei;
  const int* dst = ei + N_EDGES;

  // ---- workspace layout (≈95 MB) ----
  float* ws       = (float*)d_ws;
  float* dinv     = ws;                           // 524,288 f
  unsigned* xsb   = (unsigned*)(dinv + 524288);   // 1,048,576 u32 (2/node)
  unsigned* ub    = xsb + 1048576;                // 4,194,304 u32 (8/node)
  float* scratch  = (float*)(ub + 4194304);       // 2,000,000 f (scan scratch)
  float* sums     = scratch + 2000000;            // 16384
  int* offs       = (int*)(sums + 16384);         // 524,288 (N_NODES+1 used)
  int* ssrc       = offs + 524288;                // 8,000,000
  int* pairs      = ssrc + 8000000;               // 8,000,000
  // aliases (dead ranges reused):
  int* H    = (int*)scratch;                      // NH = 478,730
  int* Sarr = H + 478730;                         // 478,730
  int* bsum = Sarr + 478730;                      // 1871  (total 959,331 < 2,000,000)
  float* A2 = (float*)pairs;                      // pairs dead after k_csr

  hipMemsetAsync(sums, 0, (size_t)NUM_GRAPHS * 32 * 4, stream);

  const int B = 256;
  k_hist<<<NBLK_A, B, 0, stream>>>(dst, H);
  k_scan1<<<NSB, SCAN_B, 0, stream>>>(H, Sarr, bsum, NH);
  k_scan2<<<1, SCAN_B, 0, stream>>>(bsum, NSB);
  k_scatter_bkt<<<NBLK_A, B, 0, stream>>>(src, dst, Sarr, bsum, pairs);
  k_csr<<<NBKT, 1024, 0, stream>>>(pairs, Sarr, bsum, x, ssrc, offs, dinv, xsb);
  k_g1f1<<<((size_t)N_NODES * 2 + B - 1) / B, B, 0, stream>>>(ssrc, offs, xsb, dinv, W1, b1, ub);
  k_gather2<<<((size_t)N_NODES * 4 + B - 1) / B, B, 0, stream>>>(ssrc, offs, ub, A2);
  k_pool2<<<(N_NODES + 127) / 128, B, 0, stream>>>(ub, A2, W2, b2, dinv, batch, sums);
  k_mlp<<<(NUM_GRAPHS + B - 1) / B, B, 0, stream>>>(sums, batch, fW1, fb1, fW2, fb2, (float*)d_out);
}

// Round 15
// 461.912 us; speedup vs baseline: 2.3611x; 1.0262x over previous
//
#include <hip/hip_runtime.h>
#include <hip/hip_bf16.h>

constexpr int N_NODES    = 500000;
constexpr int N_EDGES    = 8000000;
constexpr int NUM_GRAPHS = 512;

constexpr int BSHIFT = 11;                              // 2048 nodes / coarse bucket
constexpr int BSIZE  = 1 << BSHIFT;
constexpr int NBKT   = (N_NODES + BSIZE - 1) / BSIZE;   // 245
constexpr int EPB    = 4096;                            // edges per block (pass A)
constexpr int NBLK_A = (N_EDGES + EPB - 1) / EPB;       // 1954
constexpr int NH     = NBKT * NBLK_A;                   // 478,730
constexpr int SCAN_B = 256;
constexpr int NSB    = (NH + SCAN_B - 1) / SCAN_B;      // 1871
constexpr int TSH    = 16;                              // src-tile = 65536 nodes (2MB of ub)

// ---- bf16 helpers (bit-level, RNE pack) ----
__device__ __forceinline__ float bf_lo(unsigned u) { return __uint_as_float(u << 16); }
__device__ __forceinline__ float bf_hi(unsigned u) { return __uint_as_float(u & 0xFFFF0000u); }
__device__ __forceinline__ unsigned short f2bf(float f) {
  unsigned u = __float_as_uint(f);
  return (unsigned short)((u + 0x7FFFu + ((u >> 16) & 1u)) >> 16);
}
__device__ __forceinline__ unsigned packbf(float a, float b) {
  return (unsigned)f2bf(a) | ((unsigned)f2bf(b) << 16);
}

// ---- pass A1: per-block coarse histogram (LDS atomics only) ----
__global__ void k_hist(const int* __restrict__ dst, int* __restrict__ H) {
  __shared__ int h[NBKT];
  for (int i = threadIdx.x; i < NBKT; i += blockDim.x) h[i] = 0;
  __syncthreads();
  int e0 = blockIdx.x * EPB;
  int e1 = min(e0 + EPB, N_EDGES);
  for (int e = e0 + threadIdx.x; e < e1; e += blockDim.x)
    atomicAdd(&h[dst[e] >> BSHIFT], 1);
  __syncthreads();
  for (int i = threadIdx.x; i < NBKT; i += blockDim.x)
    H[i * NBLK_A + blockIdx.x] = h[i];                  // bucket-major
}

// ---- exclusive scan of H: 2 kernels (scan3 folded into consumers) ----
__global__ void k_scan1(const int* __restrict__ in, int* __restrict__ out,
                        int* __restrict__ bsum, int n) {
  __shared__ int tmp[SCAN_B];
  int t = threadIdx.x;
  int i = blockIdx.x * SCAN_B + t;
  int v = (i < n) ? in[i] : 0;
  tmp[t] = v;
  __syncthreads();
  for (int off = 1; off < SCAN_B; off <<= 1) {
    int a = (t >= off) ? tmp[t - off] : 0;
    __syncthreads();
    tmp[t] += a;
    __syncthreads();
  }
  if (i < n) out[i] = tmp[t] - v;
  if (t == SCAN_B - 1) bsum[blockIdx.x] = tmp[t];
}

__global__ void k_scan2(int* __restrict__ bsum, int nb) {  // in-place exclusive
  __shared__ int tmp[SCAN_B];
  int t = threadIdx.x;
  int carry = 0;
  for (int base = 0; base < nb; base += SCAN_B) {
    int i = base + t;
    int v = (i < nb) ? bsum[i] : 0;
    tmp[t] = v;
    __syncthreads();
    for (int off = 1; off < SCAN_B; off <<= 1) {
      int a = (t >= off) ? tmp[t - off] : 0;
      __syncthreads();
      tmp[t] += a;
      __syncthreads();
    }
    if (i < nb) bsum[i] = carry + tmp[t] - v;
    carry += tmp[SCAN_B - 1];
    __syncthreads();
  }
}

// S(idx) = Sarr[idx] + bsum[idx>>8]  (scan3 inlined)
__device__ __forceinline__ int s_at(const int* Sarr, const int* bsum, int idx) {
  return Sarr[idx] + bsum[idx >> 8];
}

// ---- pass A3: block-local counting sort, then CONTIGUOUS per-bucket writes ----
__global__ void k_scatter_bkt(const int* __restrict__ src, const int* __restrict__ dst,
                              const int* __restrict__ Sarr, const int* __restrict__ bsum,
                              int* __restrict__ pairs) {
  __shared__ int lcnt[256];            // per-bucket count, then reused as cursor
  __shared__ int lofs[256];            // exclusive local scan
  __shared__ int base[256];            // global base for (bucket, this block)
  __shared__ int pout[EPB];            // reordered pairs (16 KB)
  __shared__ unsigned char bout[EPB];  // bucket id per output slot (4 KB)
  int t = threadIdx.x;
  int blk = blockIdx.x;
  int e0 = blk * EPB;
  int e1 = min(e0 + EPB, N_EDGES);
  int ne = e1 - e0;
  lcnt[t] = 0;
  __syncthreads();
  for (int e = e0 + t; e < e1; e += 256)
    atomicAdd(&lcnt[dst[e] >> BSHIFT], 1);
  __syncthreads();
  lofs[t] = lcnt[t];
  __syncthreads();
  for (int off = 1; off < 256; off <<= 1) {
    int v = (t >= off) ? lofs[t - off] : 0;
    __syncthreads();
    lofs[t] += v;
    __syncthreads();
  }
  lofs[t] -= lcnt[t];                               // exclusive
  base[t] = (t < NBKT) ? s_at(Sarr, bsum, t * NBLK_A + blk) : 0;
  lcnt[t] = 0;                                      // reuse as local cursor
  __syncthreads();
  for (int e = e0 + t; e < e1; e += 256) {
    int d = dst[e], s = src[e];
    int b = d >> BSHIFT;
    int r = atomicAdd(&lcnt[b], 1);
    int q = lofs[b] + r;
    pout[q] = ((d & (BSIZE - 1)) << 19) | s;        // s < 2^19, dlow 11 bits
    bout[q] = (unsigned char)b;                     // NBKT=245 <= 255
  }
  __syncthreads();
  for (int li = t; li < ne; li += 256) {
    int b = bout[li];
    pairs[base[b] + (li - lofs[b])] = pout[li];
  }
}

// ---- pass B: per-bucket CSR finalize with (node, src-tile) bins + FUSED prep ----
// 16K bins (64KB LDS): each node's segment is grouped by src>>16 (2MB ub tiles),
// so gather2's lockstep iterations hit a rolling 2-4MB window -> L2-resident.
__global__ void __launch_bounds__(1024)
k_csr(const int* __restrict__ pairs, const int* __restrict__ Sarr,
      const int* __restrict__ bsum, const float* __restrict__ x,
      int* __restrict__ ssrc, int* __restrict__ offs,
      float* __restrict__ dinv, unsigned* __restrict__ xsb) {
  __shared__ int hist[BSIZE * 8];      // 16384 bins, 64 KB
  __shared__ int tmp[1024];
  int t = threadIdx.x;
  int bkt = blockIdx.x;
  int n0 = bkt << BSHIFT;
  int e0 = s_at(Sarr, bsum, bkt * NBLK_A);
  int e1 = (bkt + 1 < NBKT) ? s_at(Sarr, bsum, (bkt + 1) * NBLK_A) : N_EDGES;
#pragma unroll
  for (int j = 0; j < 16; ++j) hist[t + j * 1024] = 0;
  __syncthreads();
  for (int e = e0 + t; e < e1; e += 1024) {
    int p = pairs[e];
    atomicAdd(&hist[(p >> 19) * 8 + ((p & 0x7FFFF) >> TSH)], 1);
  }
  __syncthreads();
  // thread t owns bins [16t,16t+16) = nodes n0+2t (8 tile-bins) and n0+2t+1
  int c[16];
  int tsum = 0;
#pragma unroll
  for (int j = 0; j < 16; ++j) { c[j] = hist[16 * t + j]; tsum += c[j]; }
  tmp[t] = tsum;
  __syncthreads();
  for (int off = 1; off < 1024; off <<= 1) {
    int a = (t >= off) ? tmp[t - off] : 0;
    __syncthreads();
    tmp[t] += a;
    __syncthreads();
  }
  int run = tmp[t] - tsum;             // exclusive over threads
  int c0 = c[0] + c[1] + c[2] + c[3] + c[4] + c[5] + c[6] + c[7];
  int c1 = tsum - c0;
  {
    int b = run;
#pragma unroll
    for (int j = 0; j < 16; ++j) { int cc = c[j]; hist[16 * t + j] = b; b += cc; }
  }
  int n = n0 + 2 * t;
  if (n < N_NODES) {
    offs[n] = e0 + run;
    float di = rsqrtf((float)c0 + 1.0f);
    dinv[n] = di;
    const float* xs = x + (size_t)n * 3;
    uint2 v = make_uint2(packbf(di * xs[0], di * xs[1]), packbf(di * xs[2], 0.0f));
    *(uint2*)(xsb + (size_t)n * 2) = v;
  }
  if (n + 1 < N_NODES) {
    offs[n + 1] = e0 + run + c0;
    float di = rsqrtf((float)c1 + 1.0f);
    dinv[n + 1] = di;
    const float* xs = x + (size_t)(n + 1) * 3;
    uint2 v = make_uint2(packbf(di * xs[0], di * xs[1]), packbf(di * xs[2], 0.0f));
    *(uint2*)(xsb + (size_t)(n + 1) * 2) = v;
  }
  __syncthreads();
  for (int e = e0 + t; e < e1; e += 1024) {
    int p = pairs[e];
    int r = atomicAdd(&hist[(p >> 19) * 8 + ((p & 0x7FFFF) >> TSH)], 1);
    ssrc[e0 + r] = p & 0x7FFFF;
  }
  if (bkt == 0 && t == 0) offs[N_NODES] = N_EDGES;
}

// ---- FUSED layer-1 gather + finalize: 2 lanes/node, shfl pair-exchange ----
__global__ void k_g1f1(const int* __restrict__ ssrc, const int* __restrict__ offs,
                       const unsigned* __restrict__ xsb, const float* __restrict__ dinv,
                       const float* __restrict__ W1, const float* __restrict__ b1,
                       unsigned* __restrict__ ub) {
  unsigned t = blockIdx.x * blockDim.x + threadIdx.x;
  unsigned n = t >> 1;
  int j = t & 1;
  if (n >= (unsigned)N_NODES) return;
  int o0 = offs[n], o1 = offs[n + 1];
  float a0 = 0.0f, a1 = 0.0f;
  int i = o0;
  for (; i + 1 < o1; i += 2) {
    int s0 = ssrc[i], s1 = ssrc[i + 1];
    unsigned q0 = xsb[(size_t)s0 * 2 + j];
    unsigned q1 = xsb[(size_t)s1 * 2 + j];
    a0 += bf_lo(q0) + bf_lo(q1);
    a1 += bf_hi(q0) + bf_hi(q1);
  }
  if (i < o1) {
    unsigned q = xsb[(size_t)ssrc[i] * 2 + j];
    a0 += bf_lo(q); a1 += bf_hi(q);
  }
  float oth0 = __shfl_xor(a0, 1);
  float oth1 = __shfl_xor(a1, 1);
  float A0 = j ? oth0 : a0;
  float A1v = j ? oth1 : a1;
  float A2v = j ? a0 : oth0;
  float di = dinv[n];
  uint2 xq = *(const uint2*)&xsb[(size_t)n * 2];
  float t0 = di * (A0 + bf_lo(xq.x));
  float t1 = di * (A1v + bf_hi(xq.x));
  float t2 = di * (A2v + bf_lo(xq.y));
  unsigned outv[4];
#pragma unroll
  for (int q8 = 0; q8 < 4; ++q8) {
    int f = 8 * j + 2 * q8;
    float v0 = t0 * W1[f]     + t1 * W1[16 + f]     + t2 * W1[32 + f]     + b1[f];
    float v1 = t0 * W1[f + 1] + t1 * W1[16 + f + 1] + t2 * W1[32 + f + 1] + b1[f + 1];
    outv[q8] = packbf(di * fmaxf(v0, 0.0f), di * fmaxf(v1, 0.0f));
  }
  *(uint4*)&ub[(size_t)n * 8 + j * 4] = make_uint4(outv[0], outv[1], outv[2], outv[3]);
}

// ---- layer 2 gather: 4 lanes/node, uint2 (4 bf16) per lane, unroll-2 ----
__global__ void k_gather2(const int* __restrict__ ssrc, const int* __restrict__ offs,
                          const unsigned* __restrict__ ub, float* __restrict__ A2) {
  unsigned t = blockIdx.x * blockDim.x + threadIdx.x;
  unsigned n = t >> 2;
  int j = t & 3;
  if (n >= (unsigned)N_NODES) return;
  int o0 = offs[n], o1 = offs[n + 1];
  float a0 = 0.0f, a1 = 0.0f, a2 = 0.0f, a3 = 0.0f;
  int i = o0;
  for (; i + 1 < o1; i += 2) {
    int s0 = ssrc[i], s1 = ssrc[i + 1];
    uint2 q0 = *(const uint2*)&ub[(size_t)s0 * 8 + j * 2];
    uint2 q1 = *(const uint2*)&ub[(size_t)s1 * 8 + j * 2];
    a0 += bf_lo(q0.x) + bf_lo(q1.x);
    a1 += bf_hi(q0.x) + bf_hi(q1.x);
    a2 += bf_lo(q0.y) + bf_lo(q1.y);
    a3 += bf_hi(q0.y) + bf_hi(q1.y);
  }
  if (i < o1) {
    uint2 q = *(const uint2*)&ub[(size_t)ssrc[i] * 8 + j * 2];
    a0 += bf_lo(q.x); a1 += bf_hi(q.x); a2 += bf_lo(q.y); a3 += bf_hi(q.y);
  }
  *(float4*)&A2[(size_t)n * 16 + j * 4] = make_float4(a0, a1, a2, a3);
}

// ---- pool v2: 128 contiguous nodes/block, 8 subgroups x 32 features ----
__global__ void k_pool2(const unsigned* __restrict__ ub, const float* __restrict__ A2,
                        const float* __restrict__ W2, const float* __restrict__ b2,
                        const float* __restrict__ dinv, const int* __restrict__ batch,
                        float* __restrict__ sums) {
  int f = threadIdx.x & 31, sub = threadIdx.x >> 5;
  int n0 = blockIdx.x * 128 + sub * 16;
  int n1 = min(n0 + 16, N_NODES);
  if (n0 >= n1) return;
  float w2col[16];
#pragma unroll
  for (int k = 0; k < 16; ++k) w2col[k] = W2[k * 32 + f];
  float bf = b2[f];
  int cur = batch[n0];
  float acc = 0.0f;
  for (int n = n0; n < n1; ++n) {
    int g = batch[n];
    if (g != cur) { atomicAdd(&sums[(size_t)cur * 32 + f], acc); acc = 0.0f; cur = g; }
    float di = dinv[n];
    const float4* a2p = (const float4*)(A2 + (size_t)n * 16);
    float4 aa0 = a2p[0], aa1 = a2p[1], aa2 = a2p[2], aa3 = a2p[3];
    const uint4* urp = (const uint4*)(ub + (size_t)n * 8);
    uint4 uq = urp[0], uq2 = urp[1];
    float un[16];
    un[0] = bf_lo(uq.x);  un[1] = bf_hi(uq.x);
    un[2] = bf_lo(uq.y);  un[3] = bf_hi(uq.y);
    un[4] = bf_lo(uq.z);  un[5] = bf_hi(uq.z);
    un[6] = bf_lo(uq.w);  un[7] = bf_hi(uq.w);
    un[8]  = bf_lo(uq2.x); un[9]  = bf_hi(uq2.x);
    un[10] = bf_lo(uq2.y); un[11] = bf_hi(uq2.y);
    un[12] = bf_lo(uq2.z); un[13] = bf_hi(uq2.z);
    un[14] = bf_lo(uq2.w); un[15] = bf_hi(uq2.w);
    float am[16] = {aa0.x, aa0.y, aa0.z, aa0.w, aa1.x, aa1.y, aa1.z, aa1.w,
                    aa2.x, aa2.y, aa2.z, aa2.w, aa3.x, aa3.y, aa3.z, aa3.w};
    float v = bf;
#pragma unroll
    for (int k = 0; k < 16; ++k) v += di * (am[k] + un[k]) * w2col[k];
    acc += fmaxf(v, 0.0f);
  }
  atomicAdd(&sums[(size_t)cur * 32 + f], acc);
}

// ---- final MLP + log_softmax, with FUSED segment bounds (binary search) ----
__global__ void k_mlp(const float* __restrict__ sums, const int* __restrict__ batch,
                      const float* __restrict__ fW1, const float* __restrict__ fb1,
                      const float* __restrict__ fW2, const float* __restrict__ fb2,
                      float* __restrict__ out) {
  __shared__ float w1s[32 * 64];
  __shared__ float w2s[64 * 3];
  __shared__ float b1s[64];
  __shared__ float b2s[3];
  for (int i = threadIdx.x; i < 32 * 64; i += blockDim.x) w1s[i] = fW1[i];
  for (int i = threadIdx.x; i < 64 * 3; i += blockDim.x) w2s[i] = fW2[i];
  for (int i = threadIdx.x; i < 64; i += blockDim.x) b1s[i] = fb1[i];
  for (int i = threadIdx.x; i < 3; i += blockDim.x) b2s[i] = fb2[i];
  __syncthreads();
  int g = blockIdx.x * blockDim.x + threadIdx.x;
  if (g >= NUM_GRAPHS) return;
  int lo = 0, hi = N_NODES;
  while (lo < hi) { int mid = (lo + hi) >> 1; if (batch[mid] < g) lo = mid + 1; else hi = mid; }
  int s0 = lo;
  int lo2 = s0, hi2 = N_NODES;
  while (lo2 < hi2) { int mid = (lo2 + hi2) >> 1; if (batch[mid] < g + 1) lo2 = mid + 1; else hi2 = mid; }
  float c = fmaxf((float)(lo2 - s0), 1.0f);
  float p[32];
#pragma unroll
  for (int i = 0; i < 32; ++i) p[i] = sums[(size_t)g * 32 + i] / c;
  float z2[3] = {b2s[0], b2s[1], b2s[2]};
  for (int j = 0; j < 64; ++j) {
    float a = b1s[j];
#pragma unroll
    for (int i = 0; i < 32; ++i) a += p[i] * w1s[i * 64 + j];
    a = fmaxf(a, 0.0f);
#pragma unroll
    for (int k = 0; k < 3; ++k) z2[k] += a * w2s[j * 3 + k];
  }
  float m = fmaxf(fmaxf(z2[0], z2[1]), z2[2]);
  float l = logf(expf(z2[0] - m) + expf(z2[1] - m) + expf(z2[2] - m));
#pragma unroll
  for (int k = 0; k < 3; ++k) out[(size_t)g * 3 + k] = z2[k] - m - l;
}

extern "C" void kernel_launch(void* const* d_in, const int* in_sizes, int n_in,
                              void* d_out, int out_size, void* d_ws, size_t ws_size,
                              hipStream_t stream) {
  const float* x     = (const float*)d_in[0];
  const int*   ei    = (const int*)d_in[1];   // [2, E]
  const int*   batch = (const int*)d_in[2];
  const float* W1    = (const float*)d_in[3];
  const float* b1    = (const float*)d_in[4];
  const float* W2    = (const float*)d_in[5];
  const float* b2    = (const float*)d_in[6];
  const float* fW1   = (const float*)d_in[7];
  const float* fb1   = (const float*)d_in[8];
  const float* fW2   = (const float*)d_in[9];
  const float* fb2   = (const float*)d_in[10];
  const int* src = ei;
  const int* dst = ei + N_EDGES;

  // ---- workspace layout (≈95 MB) ----
  float* ws       = (float*)d_ws;
  float* dinv     = ws;                           // 524,288 f
  unsigned* xsb   = (unsigned*)(dinv + 524288);   // 1,048,576 u32 (2/node)
  unsigned* ub    = xsb + 1048576;                // 4,194,304 u32 (8/node)
  float* scratch  = (float*)(ub + 4194304);       // 2,000,000 f (scan scratch)
  float* sums     = scratch + 2000000;            // 16384
  int* offs       = (int*)(sums + 16384);         // 524,288 (N_NODES+1 used)
  int* ssrc       = offs + 524288;                // 8,000,000
  int* pairs      = ssrc + 8000000;               // 8,000,000
  // aliases (dead ranges reused):
  int* H    = (int*)scratch;                      // NH = 478,730
  int* Sarr = H + 478730;                         // 478,730
  int* bsum = Sarr + 478730;                      // 1871  (total 959,331 < 2,000,000)
  float* A2 = (float*)pairs;                      // pairs dead after k_csr

  hipMemsetAsync(sums, 0, (size_t)NUM_GRAPHS * 32 * 4, stream);

  const int B = 256;
  k_hist<<<NBLK_A, B, 0, stream>>>(dst, H);
  k_scan1<<<NSB, SCAN_B, 0, stream>>>(H, Sarr, bsum, NH);
  k_scan2<<<1, SCAN_B, 0, stream>>>(bsum, NSB);
  k_scatter_bkt<<<NBLK_A, B, 0, stream>>>(src, dst, Sarr, bsum, pairs);
  k_csr<<<NBKT, 1024, 0, stream>>>(pairs, Sarr, bsum, x, ssrc, offs, dinv, xsb);
  k_g1f1<<<((size_t)N_NODES * 2 + B - 1) / B, B, 0, stream>>>(ssrc, offs, xsb, dinv, W1, b1, ub);
  k_gather2<<<((size_t)N_NODES * 4 + B - 1) / B, B, 0, stream>>>(ssrc, offs, ub, A2);
  k_pool2<<<(N_NODES + 127) / 128, B, 0, stream>>>(ub, A2, W2, b2, dinv, batch, sums);
  k_mlp<<<(NUM_GRAPHS + B - 1) / B, B, 0, stream>>>(sums, batch, fW1, fb1, fW2, fb2, (float*)d_out);
}